// Round 14
// baseline (3108.831 us; speedup 1.0000x reference)
//
#include <hip/hip_runtime.h>
#include <hip/hip_bf16.h>
#include <math.h>

#define VOC 50257
#define NL 12
#define NH 12
#define DM 768
#define FF 3072
#define BB 2
#define TT 1024
#define MR (BB*TT)   // 2048 rows

typedef __attribute__((ext_vector_type(8))) short bf16x8;
typedef __attribute__((ext_vector_type(4))) float f32x4;

__device__ __forceinline__ float mgelu_f(float x) {
    return 0.5f*x*(1.f + tanhf(0.7978845608028654f*(x + 0.047715f*x*x*x)));
}

__device__ __forceinline__ unsigned short f2bf(float f) {
    __hip_bfloat16 h = __float2bfloat16(f);
    return *reinterpret_cast<unsigned short*>(&h);
}

#define GLDS(gptr, lptr) __builtin_amdgcn_global_load_lds( \
    (const __attribute__((address_space(1))) void*)(gptr), \
    (__attribute__((address_space(3))) void*)(lptr), 16, 0, 0)

// XCD-chunked bijective remap (m204)
__device__ __forceinline__ int xcd_work(int bid, int total) {
    int xcd = bid & 7;
    int seq = bid >> 3;
    int q = total >> 3, r = total & 7;
    int base = (xcd < r) ? xcd*(q+1) : r + xcd*q;
    return base + seq;
}

// ---------------- embedding ----------------
__global__ void embed_kernel(const int* __restrict__ idx, const float* __restrict__ wte,
                             const float* __restrict__ wpe, float* __restrict__ x) {
    int row = blockIdx.x;
    int t = row % TT;
    int tok = idx[row];
    for (int d = threadIdx.x; d < DM; d += blockDim.x)
        x[(size_t)row*DM + d] = wte[(size_t)tok*DM + d] + wpe[(size_t)t*DM + d];
}

// ---------------- layernorm: 4 rows/block (one wave each) ----------------
__global__ __launch_bounds__(256) void ln_kernel(const float* __restrict__ x,
                          const float* __restrict__ g,
                          const float* __restrict__ b, __hip_bfloat16* __restrict__ out) {
    int row = blockIdx.x*4 + (threadIdx.x >> 6);
    int lane = threadIdx.x & 63;
    const float* xr = x + (size_t)row*DM;
    float vals[DM/64];
    float s = 0.f;
    #pragma unroll
    for (int i = 0; i < DM/64; i++) { vals[i] = xr[lane + i*64]; s += vals[i]; }
    #pragma unroll
    for (int off = 32; off > 0; off >>= 1) s += __shfl_xor(s, off);
    float mean = s * (1.0f/DM);
    float vs = 0.f;
    #pragma unroll
    for (int i = 0; i < DM/64; i++) { float d = vals[i]-mean; vs += d*d; }
    #pragma unroll
    for (int off = 32; off > 0; off >>= 1) vs += __shfl_xor(vs, off);
    float rstd = rsqrtf(vs * (1.0f/DM) + 1e-5f);
    #pragma unroll
    for (int i = 0; i < DM/64; i++) {
        int d = lane + i*64;
        out[(size_t)row*DM + d] = __float2bfloat16((vals[i]-mean)*rstd*g[d] + b[d]);
    }
}

// ---------------- one-shot transpose+cvt of ALL weights ----------------
#define TPL_QKV 1728
#define TPL_PO   576
#define TPL_FC  2304
#define TPL_PR  2304
#define TPL_LAYER (TPL_QKV + TPL_PO + TPL_FC + TPL_PR)   // 6912
#define TPL_LM  37704                                     // 1571 * 24
#define TPL_TOTAL (NL*TPL_LAYER + TPL_LM)                 // 120648

__device__ __forceinline__ void trans_one(float (*tile)[33],
                                          const float* __restrict__ in,
                                          __hip_bfloat16* __restrict__ out,
                                          int R, int C, int cx, int t) {
    int bx = t % cx, by = t / cx;
    int c0 = bx*32, r0 = by*32;
    int tx = threadIdx.x, ty = threadIdx.y;   // 32 x 8
    #pragma unroll
    for (int i = ty; i < 32; i += 8) {
        int r = r0 + i, c = c0 + tx;
        tile[i][tx] = (r < R && c < C) ? in[(size_t)r*C + c] : 0.f;
    }
    __syncthreads();
    #pragma unroll
    for (int i = ty; i < 32; i += 8) {
        int c = c0 + i, r = r0 + tx;
        if (c < C && r < R) out[(size_t)c*R + r] = __float2bfloat16(tile[tx][i]);
    }
}

__global__ void trans_all_kernel(const float* __restrict__ qkv_w, const float* __restrict__ po_w,
                                 const float* __restrict__ fc_w, const float* __restrict__ pr_w,
                                 const float* __restrict__ lm_w,
                                 __hip_bfloat16* qkv_wt, __hip_bfloat16* po_wt,
                                 __hip_bfloat16* fc_wt, __hip_bfloat16* pr_wt,
                                 __hip_bfloat16* lm_wt, float* lacc) {
    __shared__ float tile[32][33];
    int bid = blockIdx.x;
    if (bid == 0 && threadIdx.y == 0 && threadIdx.x < 2) lacc[threadIdx.x] = 0.f;
    if (bid < NL*TPL_LAYER) {
        int l = bid / TPL_LAYER;
        int r = bid - l*TPL_LAYER;
        if (r < TPL_QKV)
            trans_one(tile, qkv_w + (size_t)l*DM*3*DM, qkv_wt + (size_t)l*3*DM*DM, DM, 3*DM, 72, r);
        else if (r < TPL_QKV + TPL_PO)
            trans_one(tile, po_w + (size_t)l*DM*DM, po_wt + (size_t)l*DM*DM, DM, DM, 24, r - TPL_QKV);
        else if (r < TPL_QKV + TPL_PO + TPL_FC)
            trans_one(tile, fc_w + (size_t)l*DM*FF, fc_wt + (size_t)l*DM*FF, DM, FF, 96, r - TPL_QKV - TPL_PO);
        else
            trans_one(tile, pr_w + (size_t)l*FF*DM, pr_wt + (size_t)l*FF*DM, FF, DM, 24, r - TPL_QKV - TPL_PO - TPL_FC);
    } else {
        trans_one(tile, lm_w, lm_wt, DM, VOC, 1571, bid - NL*TPL_LAYER);
    }
}

// ---------------- MFMA bf16 GEMM, 3-slot ring + counted vmcnt (T3/T4), no setprio ----------------
// TILE: 0 = 128x128 (2x2 waves, 4x4 frags); 1 = 64x128 (1x4 waves, 4x2); 2 = 64x64 (2x2 waves, 2x2)
// MODE: 0 = f32 out, NT coalesced stores + fused LSE partials (logits, TILE0 only);
//       1 = bf16 out +bias (+V^T); 2 = f32 +bias+res; 3 = bf16 gelu+bias
template<int MODE, int TILE>
__global__ __launch_bounds__(256) void mfma_gemm_kernel(
        const __hip_bfloat16* __restrict__ A,
        const __hip_bfloat16* __restrict__ Wt,
        const float* __restrict__ bias,
        const float* __restrict__ res,
        void* __restrict__ Cout,
        __hip_bfloat16* __restrict__ vt,
        float* __restrict__ part,
        int M, int N, int K) {
    constexpr int BM  = (TILE == 0) ? 128 : 64;
    constexpr int BN  = (TILE == 2) ? 64 : 128;
    constexpr int MF  = (TILE == 2) ? 2 : 4;     // m fragments per wave
    constexpr int NF  = (TILE == 0) ? 4 : 2;     // n fragments per wave
    constexpr int WMS = (TILE == 2) ? 32 : 64;   // wave m-span
    constexpr int ABM = BM*64;                   // one A slot
    constexpr int BBM = BN*64;                   // one B slot
    constexpr int RING = 3*ABM + 3*BBM;
    constexpr int SMEMB = (MODE == 0 && RING < 34816) ? 34816 : RING;  // eps overlay
    __shared__ __align__(16) char smem[SMEMB];
    char* As = smem;
    char* Bs = smem + 3*ABM;
    int tid = threadIdx.x;
    int lane = tid & 63, wid = tid >> 6;
    int kq = lane >> 4, lr = lane & 15;

    int nby = M / BM;
    int work = xcd_work(blockIdx.x, gridDim.x);
    int by = work % nby;          // M-tile inner: consecutive works share W panel
    int bx = work / nby;
    int m0 = by * BM, n0 = bx * BN;

    int wm = (TILE == 1) ? 0 : (wid >> 1);
    int wn = (TILE == 1) ? wid : (wid & 1);
    int colbase = (TILE == 0) ? wn*64 : wn*32;

    f32x4 acc[MF][NF] = {};

    auto STAGE = [&](int slot, int k0) {
        if constexpr (TILE == 0) {
            #pragma unroll
            for (int t = 0; t < 2; t++) {
                int lx = wid + t*4;
                int r  = (lx & 1)*64 + lane;
                int kk = (lx >> 1)*8;
                GLDS(A + (size_t)(m0 + r)*K + k0 + kk, As + slot*ABM + lx*1024);
                int nr = n0 + r; if (nr > N-1) nr = N-1;
                GLDS(Wt + (size_t)nr*K + k0 + kk, Bs + slot*BBM + lx*1024);
            }
        } else if constexpr (TILE == 1) {
            GLDS(A + (size_t)(m0 + lane)*K + k0 + wid*8, As + slot*ABM + wid*1024);
            #pragma unroll
            for (int t = 0; t < 2; t++) {
                int lx = wid + t*4;
                int r  = (lx & 1)*64 + lane;
                int kk = (lx >> 1)*8;
                int nr = n0 + r; if (nr > N-1) nr = N-1;
                GLDS(Wt + (size_t)nr*K + k0 + kk, Bs + slot*BBM + lx*1024);
            }
        } else {
            GLDS(A + (size_t)(m0 + lane)*K + k0 + wid*8, As + slot*ABM + wid*1024);
            int nr = n0 + lane; if (nr > N-1) nr = N-1;
            GLDS(Wt + (size_t)nr*K + k0 + wid*8, Bs + slot*BBM + wid*1024);
        }
    };

    int nk = K >> 5;
    STAGE(0, 0);
    STAGE(1, (1 < nk ? 1 : nk-1)*32);
    for (int ki = 0; ki < nk; ++ki) {
        int cur = ki % 3;
        int k2 = (ki+2 < nk ? ki+2 : nk-1)*32;    // always-stage (clamped) -> const vmcnt
        STAGE((ki+2) % 3, k2);
        __builtin_amdgcn_sched_barrier(0);
        // 2 tiles (ki+1, ki+2) stay in flight; tile ki drained
        if constexpr (TILE == 0)      asm volatile("s_waitcnt vmcnt(8)" ::: "memory");
        else if constexpr (TILE == 1) asm volatile("s_waitcnt vmcnt(6)" ::: "memory");
        else                          asm volatile("s_waitcnt vmcnt(4)" ::: "memory");
        __builtin_amdgcn_s_barrier();             // tile ki visible to all waves
        __builtin_amdgcn_sched_barrier(0);

        bf16x8 afrag[MF], bfrag[NF];
        #pragma unroll
        for (int m = 0; m < MF; m++)
            afrag[m] = *(const bf16x8*)(As + cur*ABM + kq*(BM*16) + (wm*WMS + m*16 + lr)*16);
        #pragma unroll
        for (int n = 0; n < NF; n++)
            bfrag[n] = *(const bf16x8*)(Bs + cur*BBM + kq*(BN*16) + (colbase + n*16 + lr)*16);
        #pragma unroll
        for (int m = 0; m < MF; m++)
            #pragma unroll
            for (int n = 0; n < NF; n++)
                acc[m][n] = __builtin_amdgcn_mfma_f32_16x16x32_bf16(afrag[m], bfrag[n], acc[m][n], 0, 0, 0);

        __builtin_amdgcn_sched_barrier(0);
        asm volatile("s_waitcnt lgkmcnt(0)" ::: "memory");
        __builtin_amdgcn_s_barrier();             // WAR: slot reused by next iter's STAGE
    }

    if constexpr (MODE == 0) {
        // ---- coalesced NT epilogue + fused per-block logsumexp partials (TILE0 only)
        float* eps = (float*)smem;            // [128 rows][68 cols] f32 (stride-68)
        int nbx = (N + 127) >> 7;
        int rl2 = tid >> 1, sub = tid & 1;    // LSE ownership: thread pair per row
        float pm = -INFINITY, ps = 0.f;
        #pragma unroll
        for (int hh = 0; hh < 2; ++hh) {
            __syncthreads();                  // drains vmcnt(0): leftover stages landed
            if (wn == hh) {
                #pragma unroll
                for (int m = 0; m < 4; m++)
                    #pragma unroll
                    for (int n = 0; n < 4; n++) {
                        int cl = n*16 + lr;
                        #pragma unroll
                        for (int j = 0; j < 4; j++)
                            eps[(wm*64 + m*16 + kq*4 + j)*68 + cl] = acc[m][n][j];
                    }
            }
            __syncthreads();
            // full-line NT stores: 16 lanes x f32x4 = 256B dense per row
            #pragma unroll
            for (int it = 0; it < 8; ++it) {
                int rl = it*16 + (tid >> 4);
                int c4 = tid & 15;
                int col = n0 + hh*64 + c4*4;
                int row = m0 + rl;
                f32x4 v = *(const f32x4*)(eps + rl*68 + c4*4);
                if (col + 3 < N) {
                    __builtin_nontemporal_store(v, (f32x4*)&((float*)Cout)[(size_t)row*N + col]);
                } else {
                    #pragma unroll
                    for (int u = 0; u < 4; ++u)
                        if (col + u < N)
                            __builtin_nontemporal_store(v[u], &((float*)Cout)[(size_t)row*N + col + u]);
                }
            }
            // branch-free 2-pass LSE over this half's 32 cols per thread
            float hm = -INFINITY;
            #pragma unroll
            for (int i = 0; i < 8; ++i) {
                f32x4 v = *(const f32x4*)(eps + rl2*68 + sub*32 + i*4);
                #pragma unroll
                for (int u = 0; u < 4; ++u) {
                    int col = n0 + hh*64 + sub*32 + i*4 + u;
                    hm = fmaxf(hm, (col < N) ? v[u] : -INFINITY);
                }
            }
            float nm = fmaxf(pm, hm);
            ps *= __expf(pm - nm);
            pm = nm;
            #pragma unroll
            for (int i = 0; i < 8; ++i) {
                f32x4 v = *(const f32x4*)(eps + rl2*68 + sub*32 + i*4);
                #pragma unroll
                for (int u = 0; u < 4; ++u) {
                    int col = n0 + hh*64 + sub*32 + i*4 + u;
                    ps += __expf(((col < N) ? v[u] : -INFINITY) - pm);
                }
            }
        }
        float m2 = __shfl_xor(pm, 1), s2 = __shfl_xor(ps, 1);
        float Mx = fmaxf(pm, m2);
        float Sx = ps*__expf(pm - Mx) + s2*__expf(m2 - Mx);
        if (sub == 0)
            ((float2*)part)[(size_t)(m0 + rl2)*nbx + bx] = make_float2(Mx, Sx);
        return;
    }

    #pragma unroll
    for (int m = 0; m < MF; m++) {
        #pragma unroll
        for (int n = 0; n < NF; n++) {
            int col = n0 + colbase + n*16 + lr;
            if (col >= N) continue;
            float bv = bias[col];
            #pragma unroll
            for (int j = 0; j < 4; j++) {
                int row = m0 + wm*WMS + m*16 + kq*4 + j;
                float v = acc[m][n][j] + bv;
                size_t o = (size_t)row*N + col;
                if (MODE == 1) {
                    __hip_bfloat16 bvv = __float2bfloat16(v);
                    ((__hip_bfloat16*)Cout)[o] = bvv;
                    if (col >= 2*DM) {   // V columns -> also write V^T [b*NH+h][d][t]
                        int hh = (col - 2*DM) >> 6, dd = (col - 2*DM) & 63;
                        int bb = row >> 10, tt = row & 1023;
                        vt[(((size_t)bb*NH + hh)*64 + dd)*TT + tt] = bvv;
                    }
                } else if (MODE == 2) {
                    ((float*)Cout)[o] = v + res[o];
                } else {
                    ((__hip_bfloat16*)Cout)[o] = __float2bfloat16(mgelu_f(v));
                }
            }
        }
    }
}

// ---------------- MFMA flash attention, 3-slot ring + counted vmcnt (r11 form) ----------------
__global__ __launch_bounds__(256) void mfma_attn_kernel(const __hip_bfloat16* __restrict__ qkv,
                                                        const __hip_bfloat16* __restrict__ vt,
                                                        __hip_bfloat16* __restrict__ y) {
    __shared__ __align__(16) char K_lds[3][8192];     // [64 kv][128B d], byte ^ ((kv&7)<<4)
    __shared__ __align__(16) char VT_lds[3][8192];    // [64 d][128B kv], byte ^ ((d&7)<<4)
    __shared__ __align__(16) char P_lds[4][2048];     // per-wave [16 q][128B kv], ^ ((q&7)<<4)

    int work = xcd_work(blockIdx.x, BB*NH*16);
    int qt = 15 - (work & 15);            // LPT: heaviest q-tiles first
    int bh = work >> 4;
    int h  = bh % NH;
    int b  = bh / NH;
    int tid = threadIdx.x;
    int lane = tid & 63, w = tid >> 6;
    int lr = lane & 15, kq = lane >> 4;
    int q0 = qt * 64;

    int sr = lane >> 3;                   // staging row-within-chunk
    int scb = (lane & 7) * 16;            // staging colByte

    int qrow = q0 + w*16 + lr;
    const __hip_bfloat16* qp = qkv + (size_t)(b*TT + qrow)*3*DM + h*64;
    bf16x8 qfrag[2];
    qfrag[0] = *(const bf16x8*)(qp + kq*8);
    qfrag[1] = *(const bf16x8*)(qp + 32 + kq*8);

    f32x4 oacc[4] = {};
    float m_run = -INFINITY, l_run = 0.f;
    const float scale = 0.125f;

    const char* kbase  = (const char*)qkv + ((size_t)b*TT*3*DM + DM + h*64)*2;
    const char* vtbase = (const char*)vt + ((size_t)(b*NH + h)*64)*TT*2;

    auto STAGE = [&](int slot, int kt) {
        int kv0 = kt*64;
        #pragma unroll
        for (int t = 0; t < 2; t++) {
            int lx = w + t*4;
            int r = lx*8 + sr;
            int cbs = scb ^ ((r & 7) << 4);
            GLDS(kbase + (size_t)(kv0 + r)*3*DM*2 + cbs, K_lds[slot] + lx*1024);
            GLDS(vtbase + (size_t)r*TT*2 + kv0*2 + cbs, VT_lds[slot] + lx*1024);
        }
    };

    STAGE(0, 0);
    STAGE(1, 1 <= qt ? 1 : qt);
    for (int kt = 0; kt <= qt; ++kt) {
        int cur = kt % 3;
        STAGE((kt+2) % 3, kt+2 <= qt ? kt+2 : qt);   // always-stage (clamped)
        __builtin_amdgcn_sched_barrier(0);
        asm volatile("s_waitcnt vmcnt(8)" ::: "memory");   // tile kt landed
        __builtin_amdgcn_s_barrier();
        __builtin_amdgcn_sched_barrier(0);

        f32x4 st[4] = {};
        #pragma unroll
        for (int t = 0; t < 4; ++t) {
            #pragma unroll
            for (int ks = 0; ks < 2; ++ks) {
                int row = t*16 + lr;
                bf16x8 kf = *(const bf16x8*)(K_lds[cur] + row*128 + ((ks*64 + kq*16) ^ ((lr&7)<<4)));
                st[t] = __builtin_amdgcn_mfma_f32_16x16x32_bf16(kf, qfrag[ks], st[t], 0,0,0);
            }
        }

        float sv[4][4];
        bool diag = (kt == qt);
        float pmax = -INFINITY;
        #pragma unroll
        for (int t = 0; t < 4; ++t)
            #pragma unroll
            for (int jj = 0; jj < 4; ++jj) {
                float s = st[t][jj] * scale;
                if (diag && (t*16 + kq*4 + jj > w*16 + lr)) s = -INFINITY;
                sv[t][jj] = s;
                pmax = fmaxf(pmax, s);
            }
        pmax = fmaxf(pmax, __shfl_xor(pmax, 16));
        pmax = fmaxf(pmax, __shfl_xor(pmax, 32));
        float m_new = fmaxf(m_run, pmax);
        float corr = __expf(m_run - m_new);
        float rsum = 0.f;
        #pragma unroll
        for (int t = 0; t < 4; ++t)
            #pragma unroll
            for (int jj = 0; jj < 4; ++jj) {
                float p = __expf(sv[t][jj] - m_new);
                sv[t][jj] = p;
                rsum += p;
            }
        rsum += __shfl_xor(rsum, 16);
        rsum += __shfl_xor(rsum, 32);
        l_run = l_run * corr + rsum;
        m_run = m_new;

        #pragma unroll
        for (int jj = 0; jj < 4; ++jj) {
            float c = __shfl(corr, kq*20 + jj);
            #pragma unroll
            for (int nt = 0; nt < 4; ++nt) oacc[nt][jj] *= c;
        }

        #pragma unroll
        for (int t = 0; t < 4; ++t) {
            unsigned pk0 = (unsigned)f2bf(sv[t][0]) | ((unsigned)f2bf(sv[t][1]) << 16);
            unsigned pk1 = (unsigned)f2bf(sv[t][2]) | ((unsigned)f2bf(sv[t][3]) << 16);
            unsigned off = ((unsigned)(lr*128 + t*32 + kq*8)) ^ (((unsigned)lr&7u)<<4);
            *(uint2*)(P_lds[w] + off) = make_uint2(pk0, pk1);
        }

        #pragma unroll
        for (int ks = 0; ks < 2; ++ks) {
            bf16x8 pa = *(const bf16x8*)(P_lds[w] +
                ((unsigned)(lr*128 + ((ks*64 + kq*16) ^ ((lr&7)<<4)))));
            #pragma unroll
            for (int nt = 0; nt < 4; ++nt) {
                int row = nt*16 + lr;
                bf16x8 vf = *(const bf16x8*)(VT_lds[cur] + row*128 + ((ks*64 + kq*16) ^ ((lr&7)<<4)));
                oacc[nt] = __builtin_amdgcn_mfma_f32_16x16x32_bf16(pa, vf, oacc[nt], 0,0,0);
            }
        }

        __builtin_amdgcn_sched_barrier(0);
        asm volatile("s_waitcnt lgkmcnt(0)" ::: "memory");
        __builtin_amdgcn_s_barrier();             // WAR: slot reused next iter
    }

    #pragma unroll
    for (int jj = 0; jj < 4; ++jj) {
        float li = __shfl(l_run, kq*20 + jj);
        int qg = q0 + w*16 + kq*4 + jj;
        #pragma unroll
        for (int nt = 0; nt < 4; ++nt)
            y[(size_t)(b*TT + qg)*DM + h*64 + nt*16 + lr] =
                __float2bfloat16(oacc[nt][jj] / li);
    }
}

// ---------------- loss from fused partials: one wave per row ----------------
__global__ __launch_bounds__(64) void loss_reduce_kernel(const float* __restrict__ part,
                                                         const float* __restrict__ logits,
                                                         const int* __restrict__ targets,
                                                         float* __restrict__ acc) {
    int row = blockIdx.x;
    int lane = threadIdx.x;
    const int nbx = (VOC + 127) >> 7;   // 393
    float m = -INFINITY, s = 0.f;
    for (int bx = lane; bx < nbx; bx += 64) {
        float2 p = ((const float2*)part)[(size_t)row*nbx + bx];
        float Mx = fmaxf(m, p.x);
        s = s*__expf(m - Mx) + p.y*__expf(p.x - Mx);
        m = Mx;
    }
    #pragma unroll
    for (int off = 32; off > 0; off >>= 1) {
        float m2 = __shfl_xor(m, off), s2 = __shfl_xor(s, off);
        float Mx = fmaxf(m, m2);
        s = s*__expf(m - Mx) + s2*__expf(m2 - Mx);
        m = Mx;
    }
    if (lane == 0) {
        int tgt = targets[row];
        if (tgt >= 0) {
            float lse = logf(s) + m;
            atomicAdd(&acc[0], lse - logits[(size_t)row*VOC + tgt]);
            atomicAdd(&acc[1], 1.f);
        }
    }
}

__global__ void loss_final_kernel(const float* acc, float* out) {
    out[0] = acc[0] / acc[1];
}

// ---------------- launch ----------------
extern "C" void kernel_launch(void* const* d_in, const int* in_sizes, int n_in,
                              void* d_out, int out_size, void* d_ws, size_t ws_size,
                              hipStream_t stream) {
    const int*   idx     = (const int*)  d_in[0];
    const int*   targets = (const int*)  d_in[1];
    const float* wte     = (const float*)d_in[2];
    const float* wpe     = (const float*)d_in[3];
    const float* ln1_g   = (const float*)d_in[4];
    const float* ln1_b   = (const float*)d_in[5];
    const float* qkv_w   = (const float*)d_in[6];
    const float* qkv_b   = (const float*)d_in[7];
    const float* po_w    = (const float*)d_in[8];
    const float* po_b    = (const float*)d_in[9];
    const float* ln2_g   = (const float*)d_in[10];
    const float* ln2_b   = (const float*)d_in[11];
    const float* fc_w    = (const float*)d_in[12];
    const float* fc_b    = (const float*)d_in[13];
    const float* pr_w    = (const float*)d_in[14];
    const float* pr_b    = (const float*)d_in[15];
    const float* lnf_g   = (const float*)d_in[16];
    const float* lnf_b   = (const float*)d_in[17];
    const float* lm_w    = (const float*)d_in[18];

    float* logits = (float*)d_out;                 // [MR][VOC], loss appended

    char* p = (char*)d_ws;
    float* x = (float*)p;                 p += (size_t)MR*DM*4;
    __hip_bfloat16* h    = (__hip_bfloat16*)p; p += (size_t)MR*DM*2;
    __hip_bfloat16* qkvb = (__hip_bfloat16*)p; p += (size_t)MR*3*DM*2;
    __hip_bfloat16* yb   = (__hip_bfloat16*)p; p += (size_t)MR*DM*2;
    __hip_bfloat16* fb   = (__hip_bfloat16*)p; p += (size_t)MR*FF*2;
    __hip_bfloat16* vtb  = (__hip_bfloat16*)p; p += (size_t)BB*NH*64*TT*2;
    __hip_bfloat16* lm_wt  = (__hip_bfloat16*)p; p += (size_t)VOC*DM*2;
    __hip_bfloat16* qkv_wt = (__hip_bfloat16*)p; p += (size_t)NL*3*DM*DM*2;
    __hip_bfloat16* po_wt  = (__hip_bfloat16*)p; p += (size_t)NL*DM*DM*2;
    __hip_bfloat16* fc_wt  = (__hip_bfloat16*)p; p += (size_t)NL*DM*FF*2;
    __hip_bfloat16* pr_wt  = (__hip_bfloat16*)p; p += (size_t)NL*DM*FF*2;
    float* part = (float*)p;              p += (size_t)MR*((VOC+127)/128)*2*4;
    float* lacc = (float*)p;

    embed_kernel<<<MR, 256, 0, stream>>>(idx, wte, wpe, x);

    // one-shot: all layer weights + LM head transposed to bf16 [N][K]; zeroes lacc
    trans_all_kernel<<<TPL_TOTAL, dim3(32, 8), 0, stream>>>(
        qkv_w, po_w, fc_w, pr_w, lm_w, qkv_wt, po_wt, fc_wt, pr_wt, lm_wt, lacc);

    for (int l = 0; l < NL; l++) {
        ln_kernel<<<MR/4, 256, 0, stream>>>(x, ln1_g + l*DM, ln1_b + l*DM, h);
        mfma_gemm_kernel<1,0><<<(3*DM/128)*(MR/128), 256, 0, stream>>>(
            h, qkv_wt + (size_t)l*3*DM*DM, qkv_b + (size_t)l*3*DM, nullptr, qkvb, vtb, nullptr, MR, 3*DM, DM);
        mfma_attn_kernel<<<BB*NH*(TT/64), 256, 0, stream>>>(qkvb, vtb, yb);
        mfma_gemm_kernel<2,2><<<(DM/64)*(MR/64), 256, 0, stream>>>(
            yb, po_wt + (size_t)l*DM*DM, po_b + (size_t)l*DM, x, x, nullptr, nullptr, MR, DM, DM);
        ln_kernel<<<MR/4, 256, 0, stream>>>(x, ln2_g + l*DM, ln2_b + l*DM, h);
        mfma_gemm_kernel<3,0><<<(FF/128)*(MR/128), 256, 0, stream>>>(
            h, fc_wt + (size_t)l*DM*FF, fc_b + (size_t)l*FF, nullptr, fb, nullptr, nullptr, MR, FF, DM);
        mfma_gemm_kernel<2,2><<<(DM/64)*(MR/64), 256, 0, stream>>>(
            fb, pr_wt + (size_t)l*DM*FF, pr_b + (size_t)l*DM, x, x, nullptr, nullptr, MR, DM, FF);
    }

    ln_kernel<<<MR/4, 256, 0, stream>>>(x, lnf_g, lnf_b, h);
    mfma_gemm_kernel<0,0><<<((VOC+127)/128)*(MR/128), 256, 0, stream>>>(
        h, lm_wt, nullptr, nullptr, logits, nullptr, part, MR, VOC, DM);

    loss_reduce_kernel<<<MR, 64, 0, stream>>>(part, logits, targets, lacc);
    loss_final_kernel<<<1, 1, 0, stream>>>(lacc, logits + (size_t)MR*VOC);
}

// Round 15
// 3048.698 us; speedup vs baseline: 1.0197x; 1.0197x over previous
//
#include <hip/hip_runtime.h>
#include <hip/hip_bf16.h>
#include <math.h>

#define VOC 50257
#define NL 12
#define NH 12
#define DM 768
#define FF 3072
#define BB 2
#define TT 1024
#define MR (BB*TT)   // 2048 rows

typedef __attribute__((ext_vector_type(8))) short bf16x8;
typedef __attribute__((ext_vector_type(4))) float f32x4;

__device__ __forceinline__ float mgelu_f(float x) {
    return 0.5f*x*(1.f + tanhf(0.7978845608028654f*(x + 0.047715f*x*x*x)));
}

__device__ __forceinline__ unsigned short f2bf(float f) {
    __hip_bfloat16 h = __float2bfloat16(f);
    return *reinterpret_cast<unsigned short*>(&h);
}

#define GLDS(gptr, lptr) __builtin_amdgcn_global_load_lds( \
    (const __attribute__((address_space(1))) void*)(gptr), \
    (__attribute__((address_space(3))) void*)(lptr), 16, 0, 0)

// XCD-chunked bijective remap (m204)
__device__ __forceinline__ int xcd_work(int bid, int total) {
    int xcd = bid & 7;
    int seq = bid >> 3;
    int q = total >> 3, r = total & 7;
    int base = (xcd < r) ? xcd*(q+1) : r + xcd*q;
    return base + seq;
}

// ---------------- embedding ----------------
__global__ void embed_kernel(const int* __restrict__ idx, const float* __restrict__ wte,
                             const float* __restrict__ wpe, float* __restrict__ x) {
    int row = blockIdx.x;
    int t = row % TT;
    int tok = idx[row];
    for (int d = threadIdx.x; d < DM; d += blockDim.x)
        x[(size_t)row*DM + d] = wte[(size_t)tok*DM + d] + wpe[(size_t)t*DM + d];
}

// ---------------- layernorm: 4 rows/block (one wave each) ----------------
__global__ __launch_bounds__(256) void ln_kernel(const float* __restrict__ x,
                          const float* __restrict__ g,
                          const float* __restrict__ b, __hip_bfloat16* __restrict__ out) {
    int row = blockIdx.x*4 + (threadIdx.x >> 6);
    int lane = threadIdx.x & 63;
    const float* xr = x + (size_t)row*DM;
    float vals[DM/64];
    float s = 0.f;
    #pragma unroll
    for (int i = 0; i < DM/64; i++) { vals[i] = xr[lane + i*64]; s += vals[i]; }
    #pragma unroll
    for (int off = 32; off > 0; off >>= 1) s += __shfl_xor(s, off);
    float mean = s * (1.0f/DM);
    float vs = 0.f;
    #pragma unroll
    for (int i = 0; i < DM/64; i++) { float d = vals[i]-mean; vs += d*d; }
    #pragma unroll
    for (int off = 32; off > 0; off >>= 1) vs += __shfl_xor(vs, off);
    float rstd = rsqrtf(vs * (1.0f/DM) + 1e-5f);
    #pragma unroll
    for (int i = 0; i < DM/64; i++) {
        int d = lane + i*64;
        out[(size_t)row*DM + d] = __float2bfloat16((vals[i]-mean)*rstd*g[d] + b[d]);
    }
}

// ---------------- one-shot transpose+cvt of ALL weights ----------------
#define TPL_QKV 1728
#define TPL_PO   576
#define TPL_FC  2304
#define TPL_PR  2304
#define TPL_LAYER (TPL_QKV + TPL_PO + TPL_FC + TPL_PR)   // 6912
#define TPL_LM  37704                                     // 1571 * 24
#define TPL_TOTAL (NL*TPL_LAYER + TPL_LM)                 // 120648

__device__ __forceinline__ void trans_one(float (*tile)[33],
                                          const float* __restrict__ in,
                                          __hip_bfloat16* __restrict__ out,
                                          int R, int C, int cx, int t) {
    int bx = t % cx, by = t / cx;
    int c0 = bx*32, r0 = by*32;
    int tx = threadIdx.x, ty = threadIdx.y;   // 32 x 8
    #pragma unroll
    for (int i = ty; i < 32; i += 8) {
        int r = r0 + i, c = c0 + tx;
        tile[i][tx] = (r < R && c < C) ? in[(size_t)r*C + c] : 0.f;
    }
    __syncthreads();
    #pragma unroll
    for (int i = ty; i < 32; i += 8) {
        int c = c0 + i, r = r0 + tx;
        if (c < C && r < R) out[(size_t)c*R + r] = __float2bfloat16(tile[tx][i]);
    }
}

__global__ void trans_all_kernel(const float* __restrict__ qkv_w, const float* __restrict__ po_w,
                                 const float* __restrict__ fc_w, const float* __restrict__ pr_w,
                                 const float* __restrict__ lm_w,
                                 __hip_bfloat16* qkv_wt, __hip_bfloat16* po_wt,
                                 __hip_bfloat16* fc_wt, __hip_bfloat16* pr_wt,
                                 __hip_bfloat16* lm_wt, float* lacc) {
    __shared__ float tile[32][33];
    int bid = blockIdx.x;
    if (bid == 0 && threadIdx.y == 0 && threadIdx.x < 2) lacc[threadIdx.x] = 0.f;
    if (bid < NL*TPL_LAYER) {
        int l = bid / TPL_LAYER;
        int r = bid - l*TPL_LAYER;
        if (r < TPL_QKV)
            trans_one(tile, qkv_w + (size_t)l*DM*3*DM, qkv_wt + (size_t)l*3*DM*DM, DM, 3*DM, 72, r);
        else if (r < TPL_QKV + TPL_PO)
            trans_one(tile, po_w + (size_t)l*DM*DM, po_wt + (size_t)l*DM*DM, DM, DM, 24, r - TPL_QKV);
        else if (r < TPL_QKV + TPL_PO + TPL_FC)
            trans_one(tile, fc_w + (size_t)l*DM*FF, fc_wt + (size_t)l*DM*FF, DM, FF, 96, r - TPL_QKV - TPL_PO);
        else
            trans_one(tile, pr_w + (size_t)l*FF*DM, pr_wt + (size_t)l*FF*DM, FF, DM, 24, r - TPL_QKV - TPL_PO - TPL_FC);
    } else {
        trans_one(tile, lm_w, lm_wt, DM, VOC, 1571, bid - NL*TPL_LAYER);
    }
}

// ---------------- MFMA bf16 GEMM, 3-slot ring + SINGLE barrier per K-step ----------------
// Loop: { vmcnt(L) [tile ki landed, ki+1 in flight]; s_barrier; STAGE(ki+2); ds_read+MFMA }
// WAR safety: STAGE(ki+2) writes slot (ki-1)%3, whose readers' ds_reads completed before
// their iter-(ki-1) MFMAs issued (compiler lgkmcnt), hence before they reached barrier(ki).
// TILE: 0 = 128x128 (2x2 waves, 4x4); 1 = 64x128 (1x4 waves, 4x2); 2 = 64x64 (2x2, 2x2)
// MODE: 0 = f32 out NT coalesced + fused LSE partials (TILE0); 1 = bf16+bias (+V^T);
//       2 = f32+bias+res; 3 = bf16 gelu+bias
template<int MODE, int TILE>
__global__ __launch_bounds__(256) void mfma_gemm_kernel(
        const __hip_bfloat16* __restrict__ A,
        const __hip_bfloat16* __restrict__ Wt,
        const float* __restrict__ bias,
        const float* __restrict__ res,
        void* __restrict__ Cout,
        __hip_bfloat16* __restrict__ vt,
        float* __restrict__ part,
        int M, int N, int K) {
    constexpr int BM  = (TILE == 0) ? 128 : 64;
    constexpr int BN  = (TILE == 2) ? 64 : 128;
    constexpr int MF  = (TILE == 2) ? 2 : 4;     // m fragments per wave
    constexpr int NF  = (TILE == 0) ? 4 : 2;     // n fragments per wave
    constexpr int WMS = (TILE == 2) ? 32 : 64;   // wave m-span
    constexpr int ABM = BM*64;                   // one A slot
    constexpr int BBM = BN*64;                   // one B slot
    constexpr int RING = 3*ABM + 3*BBM;
    constexpr int SMEMB = (MODE == 0 && RING < 34816) ? 34816 : RING;  // eps overlay
    __shared__ __align__(16) char smem[SMEMB];
    char* As = smem;
    char* Bs = smem + 3*ABM;
    int tid = threadIdx.x;
    int lane = tid & 63, wid = tid >> 6;
    int kq = lane >> 4, lr = lane & 15;

    int nby = M / BM;
    int work = xcd_work(blockIdx.x, gridDim.x);
    int by = work % nby;          // M-tile inner: consecutive works share W panel
    int bx = work / nby;
    int m0 = by * BM, n0 = bx * BN;

    int wm = (TILE == 1) ? 0 : (wid >> 1);
    int wn = (TILE == 1) ? wid : (wid & 1);
    int colbase = (TILE == 0) ? wn*64 : wn*32;

    f32x4 acc[MF][NF] = {};

    auto STAGE = [&](int slot, int k0) {
        if constexpr (TILE == 0) {
            #pragma unroll
            for (int t = 0; t < 2; t++) {
                int lx = wid + t*4;
                int r  = (lx & 1)*64 + lane;
                int kk = (lx >> 1)*8;
                GLDS(A + (size_t)(m0 + r)*K + k0 + kk, As + slot*ABM + lx*1024);
                int nr = n0 + r; if (nr > N-1) nr = N-1;
                GLDS(Wt + (size_t)nr*K + k0 + kk, Bs + slot*BBM + lx*1024);
            }
        } else if constexpr (TILE == 1) {
            GLDS(A + (size_t)(m0 + lane)*K + k0 + wid*8, As + slot*ABM + wid*1024);
            #pragma unroll
            for (int t = 0; t < 2; t++) {
                int lx = wid + t*4;
                int r  = (lx & 1)*64 + lane;
                int kk = (lx >> 1)*8;
                int nr = n0 + r; if (nr > N-1) nr = N-1;
                GLDS(Wt + (size_t)nr*K + k0 + kk, Bs + slot*BBM + lx*1024);
            }
        } else {
            GLDS(A + (size_t)(m0 + lane)*K + k0 + wid*8, As + slot*ABM + wid*1024);
            int nr = n0 + lane; if (nr > N-1) nr = N-1;
            GLDS(Wt + (size_t)nr*K + k0 + wid*8, Bs + slot*BBM + wid*1024);
        }
    };

    int nk = K >> 5;
    STAGE(0, 0);
    STAGE(1, (1 < nk ? 1 : nk-1)*32);
    for (int ki = 0; ki < nk; ++ki) {
        int cur = ki % 3;
        // tile ki landed (its L loads are the oldest); tile ki+1 stays in flight
        if constexpr (TILE == 0)      asm volatile("s_waitcnt vmcnt(4)" ::: "memory");
        else if constexpr (TILE == 1) asm volatile("s_waitcnt vmcnt(3)" ::: "memory");
        else                          asm volatile("s_waitcnt vmcnt(2)" ::: "memory");
        __builtin_amdgcn_s_barrier();             // all waves: tile ki visible, slot (ki-1)%3 free
        __builtin_amdgcn_sched_barrier(0);

        int k2 = (ki+2 < nk ? ki+2 : nk-1)*32;    // always-stage (clamped) -> const vmcnt
        STAGE((ki+2) % 3, k2);

        bf16x8 afrag[MF], bfrag[NF];
        #pragma unroll
        for (int m = 0; m < MF; m++)
            afrag[m] = *(const bf16x8*)(As + cur*ABM + kq*(BM*16) + (wm*WMS + m*16 + lr)*16);
        #pragma unroll
        for (int n = 0; n < NF; n++)
            bfrag[n] = *(const bf16x8*)(Bs + cur*BBM + kq*(BN*16) + (colbase + n*16 + lr)*16);
        #pragma unroll
        for (int m = 0; m < MF; m++)
            #pragma unroll
            for (int n = 0; n < NF; n++)
                acc[m][n] = __builtin_amdgcn_mfma_f32_16x16x32_bf16(afrag[m], bfrag[n], acc[m][n], 0, 0, 0);
    }

    if constexpr (MODE == 0) {
        // ---- coalesced NT epilogue + fused per-block logsumexp partials (TILE0 only)
        float* eps = (float*)smem;            // [128 rows][68 cols] f32 (stride-68)
        int nbx = (N + 127) >> 7;
        int rl2 = tid >> 1, sub = tid & 1;    // LSE ownership: thread pair per row
        float pm = -INFINITY, ps = 0.f;
        #pragma unroll
        for (int hh = 0; hh < 2; ++hh) {
            __syncthreads();                  // drains vmcnt(0): leftover stages landed
            if (wn == hh) {
                #pragma unroll
                for (int m = 0; m < 4; m++)
                    #pragma unroll
                    for (int n = 0; n < 4; n++) {
                        int cl = n*16 + lr;
                        #pragma unroll
                        for (int j = 0; j < 4; j++)
                            eps[(wm*64 + m*16 + kq*4 + j)*68 + cl] = acc[m][n][j];
                    }
            }
            __syncthreads();
            // full-line NT stores: 16 lanes x f32x4 = 256B dense per row
            #pragma unroll
            for (int it = 0; it < 8; ++it) {
                int rl = it*16 + (tid >> 4);
                int c4 = tid & 15;
                int col = n0 + hh*64 + c4*4;
                int row = m0 + rl;
                f32x4 v = *(const f32x4*)(eps + rl*68 + c4*4);
                if (col + 3 < N) {
                    __builtin_nontemporal_store(v, (f32x4*)&((float*)Cout)[(size_t)row*N + col]);
                } else {
                    #pragma unroll
                    for (int u = 0; u < 4; ++u)
                        if (col + u < N)
                            __builtin_nontemporal_store(v[u], &((float*)Cout)[(size_t)row*N + col + u]);
                }
            }
            // branch-free 2-pass LSE over this half's 32 cols per thread
            float hm = -INFINITY;
            #pragma unroll
            for (int i = 0; i < 8; ++i) {
                f32x4 v = *(const f32x4*)(eps + rl2*68 + sub*32 + i*4);
                #pragma unroll
                for (int u = 0; u < 4; ++u) {
                    int col = n0 + hh*64 + sub*32 + i*4 + u;
                    hm = fmaxf(hm, (col < N) ? v[u] : -INFINITY);
                }
            }
            float nm = fmaxf(pm, hm);
            ps *= __expf(pm - nm);
            pm = nm;
            #pragma unroll
            for (int i = 0; i < 8; ++i) {
                f32x4 v = *(const f32x4*)(eps + rl2*68 + sub*32 + i*4);
                #pragma unroll
                for (int u = 0; u < 4; ++u) {
                    int col = n0 + hh*64 + sub*32 + i*4 + u;
                    ps += __expf(((col < N) ? v[u] : -INFINITY) - pm);
                }
            }
        }
        float m2 = __shfl_xor(pm, 1), s2 = __shfl_xor(ps, 1);
        float Mx = fmaxf(pm, m2);
        float Sx = ps*__expf(pm - Mx) + s2*__expf(m2 - Mx);
        if (sub == 0)
            ((float2*)part)[(size_t)(m0 + rl2)*nbx + bx] = make_float2(Mx, Sx);
        return;
    }

    #pragma unroll
    for (int m = 0; m < MF; m++) {
        #pragma unroll
        for (int n = 0; n < NF; n++) {
            int col = n0 + colbase + n*16 + lr;
            if (col >= N) continue;
            float bv = bias[col];
            #pragma unroll
            for (int j = 0; j < 4; j++) {
                int row = m0 + wm*WMS + m*16 + kq*4 + j;
                float v = acc[m][n][j] + bv;
                size_t o = (size_t)row*N + col;
                if (MODE == 1) {
                    __hip_bfloat16 bvv = __float2bfloat16(v);
                    ((__hip_bfloat16*)Cout)[o] = bvv;
                    if (col >= 2*DM) {   // V columns -> also write V^T [b*NH+h][d][t]
                        int hh = (col - 2*DM) >> 6, dd = (col - 2*DM) & 63;
                        int bb = row >> 10, tt = row & 1023;
                        vt[(((size_t)bb*NH + hh)*64 + dd)*TT + tt] = bvv;
                    }
                } else if (MODE == 2) {
                    ((float*)Cout)[o] = v + res[o];
                } else {
                    ((__hip_bfloat16*)Cout)[o] = __float2bfloat16(mgelu_f(v));
                }
            }
        }
    }
}

// ---------------- MFMA flash attention, 3-slot ring + single barrier per tile ----------------
__global__ __launch_bounds__(256) void mfma_attn_kernel(const __hip_bfloat16* __restrict__ qkv,
                                                        const __hip_bfloat16* __restrict__ vt,
                                                        __hip_bfloat16* __restrict__ y) {
    __shared__ __align__(16) char K_lds[3][8192];     // [64 kv][128B d], byte ^ ((kv&7)<<4)
    __shared__ __align__(16) char VT_lds[3][8192];    // [64 d][128B kv], byte ^ ((d&7)<<4)
    __shared__ __align__(16) char P_lds[4][2048];     // per-wave [16 q][128B kv], ^ ((q&7)<<4)

    int work = xcd_work(blockIdx.x, BB*NH*16);
    int qt = 15 - (work & 15);            // LPT: heaviest q-tiles first
    int bh = work >> 4;
    int h  = bh % NH;
    int b  = bh / NH;
    int tid = threadIdx.x;
    int lane = tid & 63, w = tid >> 6;
    int lr = lane & 15, kq = lane >> 4;
    int q0 = qt * 64;

    int sr = lane >> 3;                   // staging row-within-chunk
    int scb = (lane & 7) * 16;            // staging colByte

    int qrow = q0 + w*16 + lr;
    const __hip_bfloat16* qp = qkv + (size_t)(b*TT + qrow)*3*DM + h*64;
    bf16x8 qfrag[2];
    qfrag[0] = *(const bf16x8*)(qp + kq*8);
    qfrag[1] = *(const bf16x8*)(qp + 32 + kq*8);

    f32x4 oacc[4] = {};
    float m_run = -INFINITY, l_run = 0.f;
    const float scale = 0.125f;

    const char* kbase  = (const char*)qkv + ((size_t)b*TT*3*DM + DM + h*64)*2;
    const char* vtbase = (const char*)vt + ((size_t)(b*NH + h)*64)*TT*2;

    auto STAGE = [&](int slot, int kt) {
        int kv0 = kt*64;
        #pragma unroll
        for (int t = 0; t < 2; t++) {
            int lx = w + t*4;
            int r = lx*8 + sr;
            int cbs = scb ^ ((r & 7) << 4);
            GLDS(kbase + (size_t)(kv0 + r)*3*DM*2 + cbs, K_lds[slot] + lx*1024);
            GLDS(vtbase + (size_t)r*TT*2 + kv0*2 + cbs, VT_lds[slot] + lx*1024);
        }
    };

    STAGE(0, 0);
    STAGE(1, 1 <= qt ? 1 : qt);
    for (int kt = 0; kt <= qt; ++kt) {
        int cur = kt % 3;
        asm volatile("s_waitcnt vmcnt(4)" ::: "memory");   // tile kt landed; kt+1 in flight
        __builtin_amdgcn_s_barrier();
        __builtin_amdgcn_sched_barrier(0);

        STAGE((kt+2) % 3, kt+2 <= qt ? kt+2 : qt);   // always-stage (clamped)

        f32x4 st[4] = {};
        #pragma unroll
        for (int t = 0; t < 4; ++t) {
            #pragma unroll
            for (int ks = 0; ks < 2; ++ks) {
                int row = t*16 + lr;
                bf16x8 kf = *(const bf16x8*)(K_lds[cur] + row*128 + ((ks*64 + kq*16) ^ ((lr&7)<<4)));
                st[t] = __builtin_amdgcn_mfma_f32_16x16x32_bf16(kf, qfrag[ks], st[t], 0,0,0);
            }
        }

        float sv[4][4];
        bool diag = (kt == qt);
        float pmax = -INFINITY;
        #pragma unroll
        for (int t = 0; t < 4; ++t)
            #pragma unroll
            for (int jj = 0; jj < 4; ++jj) {
                float s = st[t][jj] * scale;
                if (diag && (t*16 + kq*4 + jj > w*16 + lr)) s = -INFINITY;
                sv[t][jj] = s;
                pmax = fmaxf(pmax, s);
            }
        pmax = fmaxf(pmax, __shfl_xor(pmax, 16));
        pmax = fmaxf(pmax, __shfl_xor(pmax, 32));
        float m_new = fmaxf(m_run, pmax);
        float corr = __expf(m_run - m_new);
        float rsum = 0.f;
        #pragma unroll
        for (int t = 0; t < 4; ++t)
            #pragma unroll
            for (int jj = 0; jj < 4; ++jj) {
                float p = __expf(sv[t][jj] - m_new);
                sv[t][jj] = p;
                rsum += p;
            }
        rsum += __shfl_xor(rsum, 16);
        rsum += __shfl_xor(rsum, 32);
        l_run = l_run * corr + rsum;
        m_run = m_new;

        #pragma unroll
        for (int jj = 0; jj < 4; ++jj) {
            float c = __shfl(corr, kq*20 + jj);
            #pragma unroll
            for (int nt = 0; nt < 4; ++nt) oacc[nt][jj] *= c;
        }

        #pragma unroll
        for (int t = 0; t < 4; ++t) {
            unsigned pk0 = (unsigned)f2bf(sv[t][0]) | ((unsigned)f2bf(sv[t][1]) << 16);
            unsigned pk1 = (unsigned)f2bf(sv[t][2]) | ((unsigned)f2bf(sv[t][3]) << 16);
            unsigned off = ((unsigned)(lr*128 + t*32 + kq*8)) ^ (((unsigned)lr&7u)<<4);
            *(uint2*)(P_lds[w] + off) = make_uint2(pk0, pk1);
        }

        #pragma unroll
        for (int ks = 0; ks < 2; ++ks) {
            bf16x8 pa = *(const bf16x8*)(P_lds[w] +
                ((unsigned)(lr*128 + ((ks*64 + kq*16) ^ ((lr&7)<<4)))));
            #pragma unroll
            for (int nt = 0; nt < 4; ++nt) {
                int row = nt*16 + lr;
                bf16x8 vf = *(const bf16x8*)(VT_lds[cur] + row*128 + ((ks*64 + kq*16) ^ ((lr&7)<<4)));
                oacc[nt] = __builtin_amdgcn_mfma_f32_16x16x32_bf16(pa, vf, oacc[nt], 0,0,0);
            }
        }
    }

    #pragma unroll
    for (int jj = 0; jj < 4; ++jj) {
        float li = __shfl(l_run, kq*20 + jj);
        int qg = q0 + w*16 + kq*4 + jj;
        #pragma unroll
        for (int nt = 0; nt < 4; ++nt)
            y[(size_t)(b*TT + qg)*DM + h*64 + nt*16 + lr] =
                __float2bfloat16(oacc[nt][jj] / li);
    }
}

// ---------------- loss from fused partials: one wave per row ----------------
__global__ __launch_bounds__(64) void loss_reduce_kernel(const float* __restrict__ part,
                                                         const float* __restrict__ logits,
                                                         const int* __restrict__ targets,
                                                         float* __restrict__ acc) {
    int row = blockIdx.x;
    int lane = threadIdx.x;
    const int nbx = (VOC + 127) >> 7;   // 393
    float m = -INFINITY, s = 0.f;
    for (int bx = lane; bx < nbx; bx += 64) {
        float2 p = ((const float2*)part)[(size_t)row*nbx + bx];
        float Mx = fmaxf(m, p.x);
        s = s*__expf(m - Mx) + p.y*__expf(p.x - Mx);
        m = Mx;
    }
    #pragma unroll
    for (int off = 32; off > 0; off >>= 1) {
        float m2 = __shfl_xor(m, off), s2 = __shfl_xor(s, off);
        float Mx = fmaxf(m, m2);
        s = s*__expf(m - Mx) + s2*__expf(m2 - Mx);
        m = Mx;
    }
    if (lane == 0) {
        int tgt = targets[row];
        if (tgt >= 0) {
            float lse = logf(s) + m;
            atomicAdd(&acc[0], lse - logits[(size_t)row*VOC + tgt]);
            atomicAdd(&acc[1], 1.f);
        }
    }
}

__global__ void loss_final_kernel(const float* acc, float* out) {
    out[0] = acc[0] / acc[1];
}

// ---------------- launch ----------------
extern "C" void kernel_launch(void* const* d_in, const int* in_sizes, int n_in,
                              void* d_out, int out_size, void* d_ws, size_t ws_size,
                              hipStream_t stream) {
    const int*   idx     = (const int*)  d_in[0];
    const int*   targets = (const int*)  d_in[1];
    const float* wte     = (const float*)d_in[2];
    const float* wpe     = (const float*)d_in[3];
    const float* ln1_g   = (const float*)d_in[4];
    const float* ln1_b   = (const float*)d_in[5];
    const float* qkv_w   = (const float*)d_in[6];
    const float* qkv_b   = (const float*)d_in[7];
    const float* po_w    = (const float*)d_in[8];
    const float* po_b    = (const float*)d_in[9];
    const float* ln2_g   = (const float*)d_in[10];
    const float* ln2_b   = (const float*)d_in[11];
    const float* fc_w    = (const float*)d_in[12];
    const float* fc_b    = (const float*)d_in[13];
    const float* pr_w    = (const float*)d_in[14];
    const float* pr_b    = (const float*)d_in[15];
    const float* lnf_g   = (const float*)d_in[16];
    const float* lnf_b   = (const float*)d_in[17];
    const float* lm_w    = (const float*)d_in[18];

    float* logits = (float*)d_out;                 // [MR][VOC], loss appended

    char* p = (char*)d_ws;
    float* x = (float*)p;                 p += (size_t)MR*DM*4;
    __hip_bfloat16* h    = (__hip_bfloat16*)p; p += (size_t)MR*DM*2;
    __hip_bfloat16* qkvb = (__hip_bfloat16*)p; p += (size_t)MR*3*DM*2;
    __hip_bfloat16* yb   = (__hip_bfloat16*)p; p += (size_t)MR*DM*2;
    __hip_bfloat16* fb   = (__hip_bfloat16*)p; p += (size_t)MR*FF*2;
    __hip_bfloat16* vtb  = (__hip_bfloat16*)p; p += (size_t)BB*NH*64*TT*2;
    __hip_bfloat16* lm_wt  = (__hip_bfloat16*)p; p += (size_t)VOC*DM*2;
    __hip_bfloat16* qkv_wt = (__hip_bfloat16*)p; p += (size_t)NL*3*DM*DM*2;
    __hip_bfloat16* po_wt  = (__hip_bfloat16*)p; p += (size_t)NL*DM*DM*2;
    __hip_bfloat16* fc_wt  = (__hip_bfloat16*)p; p += (size_t)NL*DM*FF*2;
    __hip_bfloat16* pr_wt  = (__hip_bfloat16*)p; p += (size_t)NL*DM*FF*2;
    float* part = (float*)p;              p += (size_t)MR*((VOC+127)/128)*2*4;
    float* lacc = (float*)p;

    embed_kernel<<<MR, 256, 0, stream>>>(idx, wte, wpe, x);

    // one-shot: all layer weights + LM head transposed to bf16 [N][K]; zeroes lacc
    trans_all_kernel<<<TPL_TOTAL, dim3(32, 8), 0, stream>>>(
        qkv_w, po_w, fc_w, pr_w, lm_w, qkv_wt, po_wt, fc_wt, pr_wt, lm_wt, lacc);

    for (int l = 0; l < NL; l++) {
        ln_kernel<<<MR/4, 256, 0, stream>>>(x, ln1_g + l*DM, ln1_b + l*DM, h);
        mfma_gemm_kernel<1,0><<<(3*DM/128)*(MR/128), 256, 0, stream>>>(
            h, qkv_wt + (size_t)l*3*DM*DM, qkv_b + (size_t)l*3*DM, nullptr, qkvb, vtb, nullptr, MR, 3*DM, DM);
        mfma_attn_kernel<<<BB*NH*(TT/64), 256, 0, stream>>>(qkvb, vtb, yb);
        mfma_gemm_kernel<2,1><<<(DM/128)*(MR/64), 256, 0, stream>>>(
            yb, po_wt + (size_t)l*DM*DM, po_b + (size_t)l*DM, x, x, nullptr, nullptr, MR, DM, DM);
        ln_kernel<<<MR/4, 256, 0, stream>>>(x, ln2_g + l*DM, ln2_b + l*DM, h);
        mfma_gemm_kernel<3,0><<<(FF/128)*(MR/128), 256, 0, stream>>>(
            h, fc_wt + (size_t)l*DM*FF, fc_b + (size_t)l*FF, nullptr, fb, nullptr, nullptr, MR, FF, DM);
        mfma_gemm_kernel<2,1><<<(DM/128)*(MR/64), 256, 0, stream>>>(
            fb, pr_wt + (size_t)l*DM*FF, pr_b + (size_t)l*DM, x, x, nullptr, nullptr, MR, DM, FF);
    }

    ln_kernel<<<MR/4, 256, 0, stream>>>(x, lnf_g, lnf_b, h);
    mfma_gemm_kernel<0,0><<<((VOC+127)/128)*(MR/128), 256, 0, stream>>>(
        h, lm_wt, nullptr, nullptr, logits, nullptr, part, MR, VOC, DM);

    loss_reduce_kernel<<<MR, 64, 0, stream>>>(part, logits, targets, lacc);
    loss_final_kernel<<<1, 1, 0, stream>>>(lacc, logits + (size_t)MR*VOC);
}

// Round 16
// 2985.117 us; speedup vs baseline: 1.0414x; 1.0213x over previous
//
#include <hip/hip_runtime.h>
#include <hip/hip_bf16.h>
#include <math.h>

#define VOC 50257
#define NL 12
#define NH 12
#define DM 768
#define FF 3072
#define BB 2
#define TT 1024
#define MR (BB*TT)   // 2048 rows

typedef __attribute__((ext_vector_type(8))) short bf16x8;
typedef __attribute__((ext_vector_type(4))) float f32x4;

__device__ __forceinline__ float mgelu_f(float x) {
    return 0.5f*x*(1.f + tanhf(0.7978845608028654f*(x + 0.047715f*x*x*x)));
}

__device__ __forceinline__ unsigned short f2bf(float f) {
    __hip_bfloat16 h = __float2bfloat16(f);
    return *reinterpret_cast<unsigned short*>(&h);
}

#define GLDS(gptr, lptr) __builtin_amdgcn_global_load_lds( \
    (const __attribute__((address_space(1))) void*)(gptr), \
    (__attribute__((address_space(3))) void*)(lptr), 16, 0, 0)

// XCD-chunked bijective remap (m204)
__device__ __forceinline__ int xcd_work(int bid, int total) {
    int xcd = bid & 7;
    int seq = bid >> 3;
    int q = total >> 3, r = total & 7;
    int base = (xcd < r) ? xcd*(q+1) : r + xcd*q;
    return base + seq;
}

// ---------------- embedding ----------------
__global__ void embed_kernel(const int* __restrict__ idx, const float* __restrict__ wte,
                             const float* __restrict__ wpe, float* __restrict__ x) {
    int row = blockIdx.x;
    int t = row % TT;
    int tok = idx[row];
    for (int d = threadIdx.x; d < DM; d += blockDim.x)
        x[(size_t)row*DM + d] = wte[(size_t)tok*DM + d] + wpe[(size_t)t*DM + d];
}

// ---------------- layernorm: 4 rows/block (one wave each) ----------------
__global__ __launch_bounds__(256) void ln_kernel(const float* __restrict__ x,
                          const float* __restrict__ g,
                          const float* __restrict__ b, __hip_bfloat16* __restrict__ out) {
    int row = blockIdx.x*4 + (threadIdx.x >> 6);
    int lane = threadIdx.x & 63;
    const float* xr = x + (size_t)row*DM;
    float vals[DM/64];
    float s = 0.f;
    #pragma unroll
    for (int i = 0; i < DM/64; i++) { vals[i] = xr[lane + i*64]; s += vals[i]; }
    #pragma unroll
    for (int off = 32; off > 0; off >>= 1) s += __shfl_xor(s, off);
    float mean = s * (1.0f/DM);
    float vs = 0.f;
    #pragma unroll
    for (int i = 0; i < DM/64; i++) { float d = vals[i]-mean; vs += d*d; }
    #pragma unroll
    for (int off = 32; off > 0; off >>= 1) vs += __shfl_xor(vs, off);
    float rstd = rsqrtf(vs * (1.0f/DM) + 1e-5f);
    #pragma unroll
    for (int i = 0; i < DM/64; i++) {
        int d = lane + i*64;
        out[(size_t)row*DM + d] = __float2bfloat16((vals[i]-mean)*rstd*g[d] + b[d]);
    }
}

// ---------------- fused 4x transpose+cvt (per-layer, keeps weights L2-hot) ----------------
struct TJob { const float* in; __hip_bfloat16* out; int R, C, cx, tile0; };

__device__ __forceinline__ void trans_one(const TJob& j, int t) {
    __shared__ float tile[32][33];
    int bx = t % j.cx, by = t / j.cx;
    int c0 = bx*32, r0 = by*32;
    int tx = threadIdx.x, ty = threadIdx.y;   // 32 x 8
    #pragma unroll
    for (int i = ty; i < 32; i += 8) {
        int r = r0 + i, c = c0 + tx;
        tile[i][tx] = (r < j.R && c < j.C) ? j.in[(size_t)r*j.C + c] : 0.f;
    }
    __syncthreads();
    #pragma unroll
    for (int i = ty; i < 32; i += 8) {
        int c = c0 + i, r = r0 + tx;
        if (c < j.C && r < j.R) j.out[(size_t)c*j.R + r] = __float2bfloat16(tile[tx][i]);
    }
}

__global__ void trans4_kernel(TJob j0, TJob j1, TJob j2, TJob j3) {
    int t = blockIdx.x;
    if (t >= j3.tile0)      trans_one(j3, t - j3.tile0);
    else if (t >= j2.tile0) trans_one(j2, t - j2.tile0);
    else if (t >= j1.tile0) trans_one(j1, t - j1.tile0);
    else                    trans_one(j0, t);
}

__global__ void trans1_kernel(TJob j0) { trans_one(j0, blockIdx.x); }

// ---------------- MFMA bf16 GEMM, slot-ring + counted vmcnt (T3/T4) ----------------
// TILE: 0 = 128x128 (3-slot, 2x2 waves, 4x4); 1 = 64x128 (3-slot, 1x4 waves, 4x2);
//       3 = 128x256 (2-slot, 2x2 waves, 4x8) -- LM head: 2x MFMA per barrier-stall
// MODE: 0 = f32 out NT coalesced + fused LSE partials (TILE3 only); 1 = bf16+bias (+V^T);
//       2 = f32+bias+res; 3 = bf16 gelu+bias
template<int MODE, int TILE>
__global__ __launch_bounds__(256) void mfma_gemm_kernel(
        const __hip_bfloat16* __restrict__ A,
        const __hip_bfloat16* __restrict__ Wt,
        const float* __restrict__ bias,
        const float* __restrict__ res,
        void* __restrict__ Cout,
        __hip_bfloat16* __restrict__ vt,
        float* __restrict__ part,
        int M, int N, int K) {
    constexpr int BM    = (TILE == 1) ? 64 : 128;
    constexpr int BN    = (TILE == 3) ? 256 : 128;
    constexpr int MF    = 4;
    constexpr int NF    = (TILE == 0) ? 4 : ((TILE == 3) ? 8 : 2);
    constexpr int SLOTS = (TILE == 3) ? 2 : 3;
    constexpr int ABM   = BM*64;                 // one A slot
    constexpr int BBM   = BN*64;                 // one B slot
    constexpr int RING  = SLOTS*(ABM + BBM);
    constexpr int SMEMB = (MODE == 0 && RING < 34816) ? 34816 : RING;
    __shared__ __align__(16) char smem[SMEMB];
    char* As = smem;
    char* Bs = smem + SLOTS*ABM;
    int tid = threadIdx.x;
    int lane = tid & 63, wid = tid >> 6;
    int kq = lane >> 4, lr = lane & 15;

    int nby = M / BM;
    int work = xcd_work(blockIdx.x, gridDim.x);
    int by = work % nby;          // M-tile inner: consecutive works share W panel
    int bx = work / nby;
    int m0 = by * BM, n0 = bx * BN;

    int wm = (TILE == 1) ? 0 : (wid >> 1);
    int wn = (TILE == 1) ? wid : (wid & 1);
    int colbase = (TILE == 0) ? wn*64 : ((TILE == 3) ? wn*128 : wn*32);

    f32x4 acc[MF][NF] = {};

    auto STAGE = [&](int slot, int k0) {
        if constexpr (TILE == 0) {
            #pragma unroll
            for (int t = 0; t < 2; t++) {
                int lx = wid + t*4;
                int r  = (lx & 1)*64 + lane;
                int kk = (lx >> 1)*8;
                GLDS(A + (size_t)(m0 + r)*K + k0 + kk, As + slot*ABM + lx*1024);
                int nr = n0 + r; if (nr > N-1) nr = N-1;
                GLDS(Wt + (size_t)nr*K + k0 + kk, Bs + slot*BBM + lx*1024);
            }
        } else if constexpr (TILE == 1) {
            GLDS(A + (size_t)(m0 + lane)*K + k0 + wid*8, As + slot*ABM + wid*1024);
            #pragma unroll
            for (int t = 0; t < 2; t++) {
                int lx = wid + t*4;
                int r  = (lx & 1)*64 + lane;
                int kk = (lx >> 1)*8;
                int nr = n0 + r; if (nr > N-1) nr = N-1;
                GLDS(Wt + (size_t)nr*K + k0 + kk, Bs + slot*BBM + lx*1024);
            }
        } else {
            // TILE3: A 8 chunks (2/wave), B 16 chunks (4/wave)
            #pragma unroll
            for (int t = 0; t < 2; t++) {
                int lx = wid + t*4;
                int r  = (lx & 1)*64 + lane;
                int kk = (lx >> 1)*8;
                GLDS(A + (size_t)(m0 + r)*K + k0 + kk, As + slot*ABM + lx*1024);
            }
            #pragma unroll
            for (int t = 0; t < 4; t++) {
                int lx = wid + t*4;               // 0..15
                int r  = (lx & 3)*64 + lane;      // B row 0..255
                int kk = (lx >> 2)*8;
                int nr = n0 + r; if (nr > N-1) nr = N-1;
                GLDS(Wt + (size_t)nr*K + k0 + kk, Bs + slot*BBM + lx*1024);
            }
        }
    };

    int nk = K >> 5;
    STAGE(0, 0);
    if constexpr (SLOTS == 3) STAGE(1, (1 < nk ? 1 : nk-1)*32);
    for (int ki = 0; ki < nk; ++ki) {
        int cur = ki % SLOTS;
        int ka = (ki+SLOTS-1 < nk ? ki+SLOTS-1 : nk-1)*32;   // always-stage (clamped)
        STAGE((ki+SLOTS-1) % SLOTS, ka);
        __builtin_amdgcn_sched_barrier(0);
        // newer tiles stay in flight; tile ki drained
        if constexpr (TILE == 0)      asm volatile("s_waitcnt vmcnt(8)" ::: "memory");
        else if constexpr (TILE == 1) asm volatile("s_waitcnt vmcnt(6)" ::: "memory");
        else                          asm volatile("s_waitcnt vmcnt(6)" ::: "memory");
        __builtin_amdgcn_s_barrier();             // tile ki visible to all waves
        __builtin_amdgcn_sched_barrier(0);

        bf16x8 afrag[MF], bfrag[NF];
        #pragma unroll
        for (int m = 0; m < MF; m++)
            afrag[m] = *(const bf16x8*)(As + cur*ABM + kq*(BM*16) + (wm*64 + m*16 + lr)*16);
        #pragma unroll
        for (int n = 0; n < NF; n++)
            bfrag[n] = *(const bf16x8*)(Bs + cur*BBM + kq*(BN*16) + (colbase + n*16 + lr)*16);
        #pragma unroll
        for (int m = 0; m < MF; m++)
            #pragma unroll
            for (int n = 0; n < NF; n++)
                acc[m][n] = __builtin_amdgcn_mfma_f32_16x16x32_bf16(afrag[m], bfrag[n], acc[m][n], 0, 0, 0);

        __builtin_amdgcn_sched_barrier(0);
        asm volatile("s_waitcnt lgkmcnt(0)" ::: "memory");
        __builtin_amdgcn_s_barrier();             // WAR: slot reused by next iter's STAGE
    }

    if constexpr (MODE == 0) {
        // ---- TILE3 epilogue: 4 x 64-col strips; NT coalesced stores + fused LSE partials
        float* eps = (float*)smem;            // [128 rows][68 cols] f32
        int nbx = (N + 255) >> 8;             // 197
        int rl2 = tid >> 1, sub = tid & 1;    // thread pair per row
        float pm = -INFINITY, ps = 0.f;
        #pragma unroll
        for (int s = 0; s < 4; ++s) {
            __syncthreads();                  // first pass: drains leftover ring stages
            if (wn == (s >> 1)) {
                #pragma unroll
                for (int m = 0; m < 4; m++)
                    #pragma unroll
                    for (int nn = 0; nn < 4; nn++) {
                        int n = (s & 1)*4 + nn;
                        int cl = nn*16 + lr;
                        #pragma unroll
                        for (int j = 0; j < 4; j++)
                            eps[(wm*64 + m*16 + kq*4 + j)*68 + cl] = acc[m][n][j];
                    }
            }
            __syncthreads();
            // full-line NT stores: 16 lanes x f32x4 = 256B dense per row
            #pragma unroll
            for (int it = 0; it < 8; ++it) {
                int rl = it*16 + (tid >> 4);
                int c4 = tid & 15;
                int col = n0 + s*64 + c4*4;
                int row = m0 + rl;
                f32x4 v = *(const f32x4*)(eps + rl*68 + c4*4);
                if (col + 3 < N) {
                    __builtin_nontemporal_store(v, (f32x4*)&((float*)Cout)[(size_t)row*N + col]);
                } else {
                    #pragma unroll
                    for (int u = 0; u < 4; ++u)
                        if (col + u < N)
                            __builtin_nontemporal_store(v[u], &((float*)Cout)[(size_t)row*N + col + u]);
                }
            }
            // branch-free 2-pass LSE over this strip's 32 cols per thread
            float hm = -INFINITY;
            #pragma unroll
            for (int i = 0; i < 8; ++i) {
                f32x4 v = *(const f32x4*)(eps + rl2*68 + sub*32 + i*4);
                #pragma unroll
                for (int u = 0; u < 4; ++u) {
                    int col = n0 + s*64 + sub*32 + i*4 + u;
                    hm = fmaxf(hm, (col < N) ? v[u] : -INFINITY);
                }
            }
            float nm = fmaxf(pm, hm);
            ps *= __expf(pm - nm);
            pm = nm;
            #pragma unroll
            for (int i = 0; i < 8; ++i) {
                f32x4 v = *(const f32x4*)(eps + rl2*68 + sub*32 + i*4);
                #pragma unroll
                for (int u = 0; u < 4; ++u) {
                    int col = n0 + s*64 + sub*32 + i*4 + u;
                    ps += __expf(((col < N) ? v[u] : -INFINITY) - pm);
                }
            }
        }
        float m2 = __shfl_xor(pm, 1), s2 = __shfl_xor(ps, 1);
        float Mx = fmaxf(pm, m2);
        float Sx = ps*__expf(pm - Mx) + s2*__expf(m2 - Mx);
        if (sub == 0)
            ((float2*)part)[(size_t)(m0 + rl2)*nbx + bx] = make_float2(Mx, Sx);
        return;
    }

    #pragma unroll
    for (int m = 0; m < MF; m++) {
        #pragma unroll
        for (int n = 0; n < NF; n++) {
            int col = n0 + colbase + n*16 + lr;
            if (col >= N) continue;
            float bv = bias[col];
            #pragma unroll
            for (int j = 0; j < 4; j++) {
                int row = m0 + wm*64 + m*16 + kq*4 + j;
                float v = acc[m][n][j] + bv;
                size_t o = (size_t)row*N + col;
                if (MODE == 1) {
                    __hip_bfloat16 bvv = __float2bfloat16(v);
                    ((__hip_bfloat16*)Cout)[o] = bvv;
                    if (col >= 2*DM) {   // V columns -> also write V^T [b*NH+h][d][t]
                        int hh = (col - 2*DM) >> 6, dd = (col - 2*DM) & 63;
                        int bb = row >> 10, tt = row & 1023;
                        vt[(((size_t)bb*NH + hh)*64 + dd)*TT + tt] = bvv;
                    }
                } else if (MODE == 2) {
                    ((float*)Cout)[o] = v + res[o];
                } else {
                    ((__hip_bfloat16*)Cout)[o] = __float2bfloat16(mgelu_f(v));
                }
            }
        }
    }
}

// ---------------- MFMA flash attention, 3-slot ring + counted vmcnt (r11 form) ----------------
__global__ __launch_bounds__(256) void mfma_attn_kernel(const __hip_bfloat16* __restrict__ qkv,
                                                        const __hip_bfloat16* __restrict__ vt,
                                                        __hip_bfloat16* __restrict__ y) {
    __shared__ __align__(16) char K_lds[3][8192];     // [64 kv][128B d], byte ^ ((kv&7)<<4)
    __shared__ __align__(16) char VT_lds[3][8192];    // [64 d][128B kv], byte ^ ((d&7)<<4)
    __shared__ __align__(16) char P_lds[4][2048];     // per-wave [16 q][128B kv], ^ ((q&7)<<4)

    int work = xcd_work(blockIdx.x, BB*NH*16);
    int qt = 15 - (work & 15);            // LPT: heaviest q-tiles first
    int bh = work >> 4;
    int h  = bh % NH;
    int b  = bh / NH;
    int tid = threadIdx.x;
    int lane = tid & 63, w = tid >> 6;
    int lr = lane & 15, kq = lane >> 4;
    int q0 = qt * 64;

    int sr = lane >> 3;                   // staging row-within-chunk
    int scb = (lane & 7) * 16;            // staging colByte

    int qrow = q0 + w*16 + lr;
    const __hip_bfloat16* qp = qkv + (size_t)(b*TT + qrow)*3*DM + h*64;
    bf16x8 qfrag[2];
    qfrag[0] = *(const bf16x8*)(qp + kq*8);
    qfrag[1] = *(const bf16x8*)(qp + 32 + kq*8);

    f32x4 oacc[4] = {};
    float m_run = -INFINITY, l_run = 0.f;
    const float scale = 0.125f;

    const char* kbase  = (const char*)qkv + ((size_t)b*TT*3*DM + DM + h*64)*2;
    const char* vtbase = (const char*)vt + ((size_t)(b*NH + h)*64)*TT*2;

    auto STAGE = [&](int slot, int kt) {
        int kv0 = kt*64;
        #pragma unroll
        for (int t = 0; t < 2; t++) {
            int lx = w + t*4;
            int r = lx*8 + sr;
            int cbs = scb ^ ((r & 7) << 4);
            GLDS(kbase + (size_t)(kv0 + r)*3*DM*2 + cbs, K_lds[slot] + lx*1024);
            GLDS(vtbase + (size_t)r*TT*2 + kv0*2 + cbs, VT_lds[slot] + lx*1024);
        }
    };

    STAGE(0, 0);
    STAGE(1, 1 <= qt ? 1 : qt);
    for (int kt = 0; kt <= qt; ++kt) {
        int cur = kt % 3;
        STAGE((kt+2) % 3, kt+2 <= qt ? kt+2 : qt);   // always-stage (clamped)
        __builtin_amdgcn_sched_barrier(0);
        asm volatile("s_waitcnt vmcnt(8)" ::: "memory");   // tile kt landed
        __builtin_amdgcn_s_barrier();
        __builtin_amdgcn_sched_barrier(0);

        f32x4 st[4] = {};
        #pragma unroll
        for (int t = 0; t < 4; ++t) {
            #pragma unroll
            for (int ks = 0; ks < 2; ++ks) {
                int row = t*16 + lr;
                bf16x8 kf = *(const bf16x8*)(K_lds[cur] + row*128 + ((ks*64 + kq*16) ^ ((lr&7)<<4)));
                st[t] = __builtin_amdgcn_mfma_f32_16x16x32_bf16(kf, qfrag[ks], st[t], 0,0,0);
            }
        }

        float sv[4][4];
        bool diag = (kt == qt);
        float pmax = -INFINITY;
        #pragma unroll
        for (int t = 0; t < 4; ++t)
            #pragma unroll
            for (int jj = 0; jj < 4; ++jj) {
                float s = st[t][jj] * scale;
                if (diag && (t*16 + kq*4 + jj > w*16 + lr)) s = -INFINITY;
                sv[t][jj] = s;
                pmax = fmaxf(pmax, s);
            }
        pmax = fmaxf(pmax, __shfl_xor(pmax, 16));
        pmax = fmaxf(pmax, __shfl_xor(pmax, 32));
        float m_new = fmaxf(m_run, pmax);
        float corr = __expf(m_run - m_new);
        float rsum = 0.f;
        #pragma unroll
        for (int t = 0; t < 4; ++t)
            #pragma unroll
            for (int jj = 0; jj < 4; ++jj) {
                float p = __expf(sv[t][jj] - m_new);
                sv[t][jj] = p;
                rsum += p;
            }
        rsum += __shfl_xor(rsum, 16);
        rsum += __shfl_xor(rsum, 32);
        l_run = l_run * corr + rsum;
        m_run = m_new;

        #pragma unroll
        for (int jj = 0; jj < 4; ++jj) {
            float c = __shfl(corr, kq*20 + jj);
            #pragma unroll
            for (int nt = 0; nt < 4; ++nt) oacc[nt][jj] *= c;
        }

        #pragma unroll
        for (int t = 0; t < 4; ++t) {
            unsigned pk0 = (unsigned)f2bf(sv[t][0]) | ((unsigned)f2bf(sv[t][1]) << 16);
            unsigned pk1 = (unsigned)f2bf(sv[t][2]) | ((unsigned)f2bf(sv[t][3]) << 16);
            unsigned off = ((unsigned)(lr*128 + t*32 + kq*8)) ^ (((unsigned)lr&7u)<<4);
            *(uint2*)(P_lds[w] + off) = make_uint2(pk0, pk1);
        }

        #pragma unroll
        for (int ks = 0; ks < 2; ++ks) {
            bf16x8 pa = *(const bf16x8*)(P_lds[w] +
                ((unsigned)(lr*128 + ((ks*64 + kq*16) ^ ((lr&7)<<4)))));
            #pragma unroll
            for (int nt = 0; nt < 4; ++nt) {
                int row = nt*16 + lr;
                bf16x8 vf = *(const bf16x8*)(VT_lds[cur] + row*128 + ((ks*64 + kq*16) ^ ((lr&7)<<4)));
                oacc[nt] = __builtin_amdgcn_mfma_f32_16x16x32_bf16(pa, vf, oacc[nt], 0,0,0);
            }
        }

        __builtin_amdgcn_sched_barrier(0);
        asm volatile("s_waitcnt lgkmcnt(0)" ::: "memory");
        __builtin_amdgcn_s_barrier();             // WAR: slot reused next iter
    }

    #pragma unroll
    for (int jj = 0; jj < 4; ++jj) {
        float li = __shfl(l_run, kq*20 + jj);
        int qg = q0 + w*16 + kq*4 + jj;
        #pragma unroll
        for (int nt = 0; nt < 4; ++nt)
            y[(size_t)(b*TT + qg)*DM + h*64 + nt*16 + lr] =
                __float2bfloat16(oacc[nt][jj] / li);
    }
}

// ---------------- loss from fused partials: one wave per row ----------------
__global__ void zero_acc_kernel(float* p) { p[threadIdx.x] = 0.f; }

__global__ __launch_bounds__(64) void loss_reduce_kernel(const float* __restrict__ part,
                                                         const float* __restrict__ logits,
                                                         const int* __restrict__ targets,
                                                         float* __restrict__ acc) {
    int row = blockIdx.x;
    int lane = threadIdx.x;
    const int nbx = (VOC + 255) >> 8;   // 197
    float m = -INFINITY, s = 0.f;
    for (int bx = lane; bx < nbx; bx += 64) {
        float2 p = ((const float2*)part)[(size_t)row*nbx + bx];
        float Mx = fmaxf(m, p.x);
        s = s*__expf(m - Mx) + p.y*__expf(p.x - Mx);
        m = Mx;
    }
    #pragma unroll
    for (int off = 32; off > 0; off >>= 1) {
        float m2 = __shfl_xor(m, off), s2 = __shfl_xor(s, off);
        float Mx = fmaxf(m, m2);
        s = s*__expf(m - Mx) + s2*__expf(m2 - Mx);
        m = Mx;
    }
    if (lane == 0) {
        int tgt = targets[row];
        if (tgt >= 0) {
            float lse = logf(s) + m;
            atomicAdd(&acc[0], lse - logits[(size_t)row*VOC + tgt]);
            atomicAdd(&acc[1], 1.f);
        }
    }
}

__global__ void loss_final_kernel(const float* acc, float* out) {
    out[0] = acc[0] / acc[1];
}

// ---------------- launch ----------------
static inline TJob mkjob(const float* in, __hip_bfloat16* out, int R, int C, int tile0) {
    TJob j; j.in = in; j.out = out; j.R = R; j.C = C;
    j.cx = (C + 31)/32; j.tile0 = tile0;
    return j;
}

extern "C" void kernel_launch(void* const* d_in, const int* in_sizes, int n_in,
                              void* d_out, int out_size, void* d_ws, size_t ws_size,
                              hipStream_t stream) {
    const int*   idx     = (const int*)  d_in[0];
    const int*   targets = (const int*)  d_in[1];
    const float* wte     = (const float*)d_in[2];
    const float* wpe     = (const float*)d_in[3];
    const float* ln1_g   = (const float*)d_in[4];
    const float* ln1_b   = (const float*)d_in[5];
    const float* qkv_w   = (const float*)d_in[6];
    const float* qkv_b   = (const float*)d_in[7];
    const float* po_w    = (const float*)d_in[8];
    const float* po_b    = (const float*)d_in[9];
    const float* ln2_g   = (const float*)d_in[10];
    const float* ln2_b   = (const float*)d_in[11];
    const float* fc_w    = (const float*)d_in[12];
    const float* fc_b    = (const float*)d_in[13];
    const float* pr_w    = (const float*)d_in[14];
    const float* pr_b    = (const float*)d_in[15];
    const float* lnf_g   = (const float*)d_in[16];
    const float* lnf_b   = (const float*)d_in[17];
    const float* lm_w    = (const float*)d_in[18];

    float* logits = (float*)d_out;                 // [MR][VOC], loss appended

    char* p = (char*)d_ws;
    float* x = (float*)p;                 p += (size_t)MR*DM*4;
    __hip_bfloat16* h    = (__hip_bfloat16*)p; p += (size_t)MR*DM*2;
    __hip_bfloat16* qkvb = (__hip_bfloat16*)p; p += (size_t)MR*3*DM*2;
    __hip_bfloat16* yb   = (__hip_bfloat16*)p; p += (size_t)MR*DM*2;
    __hip_bfloat16* fb   = (__hip_bfloat16*)p; p += (size_t)MR*FF*2;
    __hip_bfloat16* vtb  = (__hip_bfloat16*)p; p += (size_t)BB*NH*64*TT*2;
    __hip_bfloat16* lm_wt  = (__hip_bfloat16*)p; p += (size_t)VOC*DM*2;
    __hip_bfloat16* qkv_wt = (__hip_bfloat16*)p; p += (size_t)3*DM*DM*2;
    __hip_bfloat16* po_wt  = (__hip_bfloat16*)p; p += (size_t)DM*DM*2;
    __hip_bfloat16* fc_wt  = (__hip_bfloat16*)p; p += (size_t)FF*DM*2;
    __hip_bfloat16* pr_wt  = (__hip_bfloat16*)p; p += (size_t)DM*FF*2;
    float* part = (float*)p;              p += (size_t)MR*((VOC+255)/256)*2*4;
    float* lacc = (float*)p;

    dim3 tpb(32, 8);

    embed_kernel<<<MR, 256, 0, stream>>>(idx, wte, wpe, x);

    {
        TJob j = mkjob(lm_w, lm_wt, DM, VOC, 0);
        int tiles = j.cx * ((DM+31)/32);
        trans1_kernel<<<tiles, tpb, 0, stream>>>(j);
    }

    for (int l = 0; l < NL; l++) {
        TJob j0 = mkjob(qkv_w + (size_t)l*DM*3*DM, qkv_wt, DM, 3*DM, 0);
        int t1 = j0.cx * 24;
        TJob j1 = mkjob(po_w + (size_t)l*DM*DM, po_wt, DM, DM, t1);
        int t2 = t1 + j1.cx * 24;
        TJob j2 = mkjob(fc_w + (size_t)l*DM*FF, fc_wt, DM, FF, t2);
        int t3 = t2 + j2.cx * 24;
        TJob j3 = mkjob(pr_w + (size_t)l*FF*DM, pr_wt, FF, DM, t3);
        int tot = t3 + j3.cx * 96;
        trans4_kernel<<<tot, tpb, 0, stream>>>(j0, j1, j2, j3);

        ln_kernel<<<MR/4, 256, 0, stream>>>(x, ln1_g + l*DM, ln1_b + l*DM, h);
        mfma_gemm_kernel<1,0><<<(3*DM/128)*(MR/128), 256, 0, stream>>>(
            h, qkv_wt, qkv_b + (size_t)l*3*DM, nullptr, qkvb, vtb, nullptr, MR, 3*DM, DM);
        mfma_attn_kernel<<<BB*NH*(TT/64), 256, 0, stream>>>(qkvb, vtb, yb);
        mfma_gemm_kernel<2,1><<<(DM/128)*(MR/64), 256, 0, stream>>>(
            yb, po_wt, po_b + (size_t)l*DM, x, x, nullptr, nullptr, MR, DM, DM);
        ln_kernel<<<MR/4, 256, 0, stream>>>(x, ln2_g + l*DM, ln2_b + l*DM, h);
        mfma_gemm_kernel<3,0><<<(FF/128)*(MR/128), 256, 0, stream>>>(
            h, fc_wt, fc_b + (size_t)l*FF, nullptr, fb, nullptr, nullptr, MR, FF, DM);
        mfma_gemm_kernel<2,1><<<(DM/128)*(MR/64), 256, 0, stream>>>(
            fb, pr_wt, pr_b + (size_t)l*DM, x, x, nullptr, nullptr, MR, DM, FF);
    }

    ln_kernel<<<MR/4, 256, 0, stream>>>(x, lnf_g, lnf_b, h);
    mfma_gemm_kernel<0,3><<<((VOC+255)/256)*(MR/128), 256, 0, stream>>>(
        h, lm_wt, nullptr, nullptr, logits, nullptr, part, MR, VOC, DM);

    zero_acc_kernel<<<1, 2, 0, stream>>>(lacc);
    loss_reduce_kernel<<<MR, 64, 0, stream>>>(part, logits, targets, lacc);
    loss_final_kernel<<<1, 1, 0, stream>>>(lacc, logits + (size_t)MR*VOC);
}

// Round 17
// 2859.984 us; speedup vs baseline: 1.0870x; 1.0438x over previous
//
#include <hip/hip_runtime.h>
#include <hip/hip_bf16.h>
#include <math.h>

#define VOC 50257
#define NL 12
#define NH 12
#define DM 768
#define FF 3072
#define BB 2
#define TT 1024
#define MR (BB*TT)   // 2048 rows

typedef __attribute__((ext_vector_type(8))) short bf16x8;
typedef __attribute__((ext_vector_type(4))) float f32x4;

__device__ __forceinline__ float mgelu_f(float x) {
    return 0.5f*x*(1.f + tanhf(0.7978845608028654f*(x + 0.047715f*x*x*x)));
}

__device__ __forceinline__ unsigned short f2bf(float f) {
    __hip_bfloat16 h = __float2bfloat16(f);
    return *reinterpret_cast<unsigned short*>(&h);
}

#define GLDS(gptr, lptr) __builtin_amdgcn_global_load_lds( \
    (const __attribute__((address_space(1))) void*)(gptr), \
    (__attribute__((address_space(3))) void*)(lptr), 16, 0, 0)

// XCD-chunked bijective remap (m204)
__device__ __forceinline__ int xcd_work(int bid, int total) {
    int xcd = bid & 7;
    int seq = bid >> 3;
    int q = total >> 3, r = total & 7;
    int base = (xcd < r) ? xcd*(q+1) : r + xcd*q;
    return base + seq;
}

// ---------------- embedding ----------------
__global__ void embed_kernel(const int* __restrict__ idx, const float* __restrict__ wte,
                             const float* __restrict__ wpe, float* __restrict__ x) {
    int row = blockIdx.x;
    int t = row % TT;
    int tok = idx[row];
    for (int d = threadIdx.x; d < DM; d += blockDim.x)
        x[(size_t)row*DM + d] = wte[(size_t)tok*DM + d] + wpe[(size_t)t*DM + d];
}

// ---------------- layernorm: 4 rows/block (one wave each) ----------------
__global__ __launch_bounds__(256) void ln_kernel(const float* __restrict__ x,
                          const float* __restrict__ g,
                          const float* __restrict__ b, __hip_bfloat16* __restrict__ out) {
    int row = blockIdx.x*4 + (threadIdx.x >> 6);
    int lane = threadIdx.x & 63;
    const float* xr = x + (size_t)row*DM;
    float vals[DM/64];
    float s = 0.f;
    #pragma unroll
    for (int i = 0; i < DM/64; i++) { vals[i] = xr[lane + i*64]; s += vals[i]; }
    #pragma unroll
    for (int off = 32; off > 0; off >>= 1) s += __shfl_xor(s, off);
    float mean = s * (1.0f/DM);
    float vs = 0.f;
    #pragma unroll
    for (int i = 0; i < DM/64; i++) { float d = vals[i]-mean; vs += d*d; }
    #pragma unroll
    for (int off = 32; off > 0; off >>= 1) vs += __shfl_xor(vs, off);
    float rstd = rsqrtf(vs * (1.0f/DM) + 1e-5f);
    #pragma unroll
    for (int i = 0; i < DM/64; i++) {
        int d = lane + i*64;
        out[(size_t)row*DM + d] = __float2bfloat16((vals[i]-mean)*rstd*g[d] + b[d]);
    }
}

// ---------------- fused 4x transpose+cvt (per-layer, keeps weights L2-hot) ----------------
struct TJob { const float* in; __hip_bfloat16* out; int R, C, cx, tile0; };

__device__ __forceinline__ void trans_one(const TJob& j, int t) {
    __shared__ float tile[32][33];
    int bx = t % j.cx, by = t / j.cx;
    int c0 = bx*32, r0 = by*32;
    int tx = threadIdx.x, ty = threadIdx.y;   // 32 x 8
    #pragma unroll
    for (int i = ty; i < 32; i += 8) {
        int r = r0 + i, c = c0 + tx;
        tile[i][tx] = (r < j.R && c < j.C) ? j.in[(size_t)r*j.C + c] : 0.f;
    }
    __syncthreads();
    #pragma unroll
    for (int i = ty; i < 32; i += 8) {
        int c = c0 + i, r = r0 + tx;
        if (c < j.C && r < j.R) j.out[(size_t)c*j.R + r] = __float2bfloat16(tile[tx][i]);
    }
}

__global__ void trans4_kernel(TJob j0, TJob j1, TJob j2, TJob j3) {
    int t = blockIdx.x;
    if (t >= j3.tile0)      trans_one(j3, t - j3.tile0);
    else if (t >= j2.tile0) trans_one(j2, t - j2.tile0);
    else if (t >= j1.tile0) trans_one(j1, t - j1.tile0);
    else                    trans_one(j0, t);
}

__global__ void trans1_kernel(TJob j0) { trans_one(j0, blockIdx.x); }

// ---------------- MFMA bf16 GEMM, 3-slot ring + counted vmcnt (T3/T4), no setprio ----------------
// TILE: 0 = 128x128 (2x2 waves, 4x4); 1 = 64x128 (1x4 waves, 4x2)
// MODE: 0 = f32 out NT coalesced + fused LSE partials (TILE0); 1 = bf16+bias (+V^T);
//       2 = f32+bias+res; 3 = bf16 gelu+bias
template<int MODE, int TILE>
__global__ __launch_bounds__(256) void mfma_gemm_kernel(
        const __hip_bfloat16* __restrict__ A,
        const __hip_bfloat16* __restrict__ Wt,
        const float* __restrict__ bias,
        const float* __restrict__ res,
        void* __restrict__ Cout,
        __hip_bfloat16* __restrict__ vt,
        float* __restrict__ part,
        int M, int N, int K) {
    constexpr int BM  = (TILE == 1) ? 64 : 128;
    constexpr int MF  = 4;
    constexpr int NF  = (TILE == 0) ? 4 : 2;
    constexpr int ABM = BM*64;                    // one A slot
    constexpr int RING = 3*ABM + 3*8192;
    constexpr int SMEMB = (MODE == 0 && RING < 34816) ? 34816 : RING;  // eps overlay
    __shared__ __align__(16) char smem[SMEMB];
    char* As = smem;
    char* Bs = smem + 3*ABM;
    int tid = threadIdx.x;
    int lane = tid & 63, wid = tid >> 6;
    int kq = lane >> 4, lr = lane & 15;

    int nby = M / BM;
    int work = xcd_work(blockIdx.x, gridDim.x);
    int by = work % nby;          // M-tile inner: consecutive works share W panel
    int bx = work / nby;
    int m0 = by * BM, n0 = bx * 128;

    int wm = (TILE == 1) ? 0 : (wid >> 1);
    int wn = (TILE == 1) ? wid : (wid & 1);
    int colbase = (TILE == 0) ? wn*64 : wn*32;

    f32x4 acc[MF][NF] = {};

    auto STAGE = [&](int slot, int k0) {
        if constexpr (TILE == 0) {
            #pragma unroll
            for (int t = 0; t < 2; t++) {
                int lx = wid + t*4;
                int r  = (lx & 1)*64 + lane;
                int kk = (lx >> 1)*8;
                GLDS(A + (size_t)(m0 + r)*K + k0 + kk, As + slot*ABM + lx*1024);
                int nr = n0 + r; if (nr > N-1) nr = N-1;
                GLDS(Wt + (size_t)nr*K + k0 + kk, Bs + slot*8192 + lx*1024);
            }
        } else {
            GLDS(A + (size_t)(m0 + lane)*K + k0 + wid*8, As + slot*ABM + wid*1024);
            #pragma unroll
            for (int t = 0; t < 2; t++) {
                int lx = wid + t*4;
                int r  = (lx & 1)*64 + lane;
                int kk = (lx >> 1)*8;
                int nr = n0 + r; if (nr > N-1) nr = N-1;
                GLDS(Wt + (size_t)nr*K + k0 + kk, Bs + slot*8192 + lx*1024);
            }
        }
    };

    int nk = K >> 5;
    STAGE(0, 0);
    STAGE(1, (1 < nk ? 1 : nk-1)*32);
    for (int ki = 0; ki < nk; ++ki) {
        int cur = ki % 3;
        int k2 = (ki+2 < nk ? ki+2 : nk-1)*32;    // always-stage (clamped) -> const vmcnt
        STAGE((ki+2) % 3, k2);
        __builtin_amdgcn_sched_barrier(0);
        // tiles ki+1, ki+2 stay in flight; everything older (incl. tile ki) drained
        if constexpr (TILE == 0) asm volatile("s_waitcnt vmcnt(8)" ::: "memory");
        else                     asm volatile("s_waitcnt vmcnt(6)" ::: "memory");
        __builtin_amdgcn_s_barrier();             // tile ki visible to all waves
        __builtin_amdgcn_sched_barrier(0);

        bf16x8 afrag[MF], bfrag[NF];
        #pragma unroll
        for (int m = 0; m < MF; m++)
            afrag[m] = *(const bf16x8*)(As + cur*ABM + kq*(BM*16) + (wm*64 + m*16 + lr)*16);
        #pragma unroll
        for (int n = 0; n < NF; n++)
            bfrag[n] = *(const bf16x8*)(Bs + cur*8192 + kq*2048 + (colbase + n*16 + lr)*16);
        #pragma unroll
        for (int m = 0; m < MF; m++)
            #pragma unroll
            for (int n = 0; n < NF; n++)
                acc[m][n] = __builtin_amdgcn_mfma_f32_16x16x32_bf16(afrag[m], bfrag[n], acc[m][n], 0, 0, 0);

        __builtin_amdgcn_sched_barrier(0);
        asm volatile("s_waitcnt lgkmcnt(0)" ::: "memory");
        __builtin_amdgcn_s_barrier();             // WAR: slot reused by next iter's STAGE
    }

    if constexpr (MODE == 0) {
        // ---- coalesced NT epilogue + fused per-block logsumexp partials (TILE0 only)
        float* eps = (float*)smem;            // [128 rows][68 cols] f32 (stride-68)
        int nbx = (N + 127) >> 7;
        int rl2 = tid >> 1, sub = tid & 1;    // LSE ownership: thread pair per row
        float pm = -INFINITY, ps = 0.f;
        #pragma unroll
        for (int hh = 0; hh < 2; ++hh) {
            __syncthreads();                  // drains vmcnt(0): leftover ring stages landed
            if (wn == hh) {
                #pragma unroll
                for (int m = 0; m < 4; m++)
                    #pragma unroll
                    for (int n = 0; n < 4; n++) {
                        int cl = n*16 + lr;
                        #pragma unroll
                        for (int j = 0; j < 4; j++)
                            eps[(wm*64 + m*16 + kq*4 + j)*68 + cl] = acc[m][n][j];
                    }
            }
            __syncthreads();
            // full-line NT stores: 16 lanes x f32x4 = 256B dense per row
            #pragma unroll
            for (int it = 0; it < 8; ++it) {
                int rl = it*16 + (tid >> 4);
                int c4 = tid & 15;
                int col = n0 + hh*64 + c4*4;
                int row = m0 + rl;
                f32x4 v = *(const f32x4*)(eps + rl*68 + c4*4);
                if (col + 3 < N) {
                    __builtin_nontemporal_store(v, (f32x4*)&((float*)Cout)[(size_t)row*N + col]);
                } else {
                    #pragma unroll
                    for (int u = 0; u < 4; ++u)
                        if (col + u < N)
                            __builtin_nontemporal_store(v[u], &((float*)Cout)[(size_t)row*N + col + u]);
                }
            }
            // branch-free 2-pass LSE over this half's 32 cols per thread
            float hm = -INFINITY;
            #pragma unroll
            for (int i = 0; i < 8; ++i) {
                f32x4 v = *(const f32x4*)(eps + rl2*68 + sub*32 + i*4);
                #pragma unroll
                for (int u = 0; u < 4; ++u) {
                    int col = n0 + hh*64 + sub*32 + i*4 + u;
                    hm = fmaxf(hm, (col < N) ? v[u] : -INFINITY);
                }
            }
            float nm = fmaxf(pm, hm);
            ps *= __expf(pm - nm);
            pm = nm;
            #pragma unroll
            for (int i = 0; i < 8; ++i) {
                f32x4 v = *(const f32x4*)(eps + rl2*68 + sub*32 + i*4);
                #pragma unroll
                for (int u = 0; u < 4; ++u) {
                    int col = n0 + hh*64 + sub*32 + i*4 + u;
                    ps += __expf(((col < N) ? v[u] : -INFINITY) - pm);
                }
            }
        }
        float m2 = __shfl_xor(pm, 1), s2 = __shfl_xor(ps, 1);
        float Mx = fmaxf(pm, m2);
        float Sx = ps*__expf(pm - Mx) + s2*__expf(m2 - Mx);
        if (sub == 0)
            ((float2*)part)[(size_t)(m0 + rl2)*nbx + bx] = make_float2(Mx, Sx);
        return;
    }

    #pragma unroll
    for (int m = 0; m < MF; m++) {
        #pragma unroll
        for (int n = 0; n < NF; n++) {
            int col = n0 + colbase + n*16 + lr;
            if (col >= N) continue;
            float bv = bias[col];
            #pragma unroll
            for (int j = 0; j < 4; j++) {
                int row = m0 + wm*64 + m*16 + kq*4 + j;
                float v = acc[m][n][j] + bv;
                size_t o = (size_t)row*N + col;
                if (MODE == 1) {
                    __hip_bfloat16 bvv = __float2bfloat16(v);
                    ((__hip_bfloat16*)Cout)[o] = bvv;
                    if (col >= 2*DM) {   // V columns -> also write V^T [b*NH+h][d][t]
                        int hh = (col - 2*DM) >> 6, dd = (col - 2*DM) & 63;
                        int bb = row >> 10, tt = row & 1023;
                        vt[(((size_t)bb*NH + hh)*64 + dd)*TT + tt] = bvv;
                    }
                } else if (MODE == 2) {
                    ((float*)Cout)[o] = v + res[o];
                } else {
                    ((__hip_bfloat16*)Cout)[o] = __float2bfloat16(mgelu_f(v));
                }
            }
        }
    }
}

// ---------------- MFMA flash attention, 3-slot ring + counted vmcnt (r11 form) ----------------
__global__ __launch_bounds__(256) void mfma_attn_kernel(const __hip_bfloat16* __restrict__ qkv,
                                                        const __hip_bfloat16* __restrict__ vt,
                                                        __hip_bfloat16* __restrict__ y) {
    __shared__ __align__(16) char K_lds[3][8192];     // [64 kv][128B d], byte ^ ((kv&7)<<4)
    __shared__ __align__(16) char VT_lds[3][8192];    // [64 d][128B kv], byte ^ ((d&7)<<4)
    __shared__ __align__(16) char P_lds[4][2048];     // per-wave [16 q][128B kv], ^ ((q&7)<<4)

    int work = xcd_work(blockIdx.x, BB*NH*16);
    int qt = 15 - (work & 15);            // LPT: heaviest q-tiles first
    int bh = work >> 4;
    int h  = bh % NH;
    int b  = bh / NH;
    int tid = threadIdx.x;
    int lane = tid & 63, w = tid >> 6;
    int lr = lane & 15, kq = lane >> 4;
    int q0 = qt * 64;

    int sr = lane >> 3;                   // staging row-within-chunk
    int scb = (lane & 7) * 16;            // staging colByte

    int qrow = q0 + w*16 + lr;
    const __hip_bfloat16* qp = qkv + (size_t)(b*TT + qrow)*3*DM + h*64;
    bf16x8 qfrag[2];
    qfrag[0] = *(const bf16x8*)(qp + kq*8);
    qfrag[1] = *(const bf16x8*)(qp + 32 + kq*8);

    f32x4 oacc[4] = {};
    float m_run = -INFINITY, l_run = 0.f;
    const float scale = 0.125f;

    const char* kbase  = (const char*)qkv + ((size_t)b*TT*3*DM + DM + h*64)*2;
    const char* vtbase = (const char*)vt + ((size_t)(b*NH + h)*64)*TT*2;

    auto STAGE = [&](int slot, int kt) {
        int kv0 = kt*64;
        #pragma unroll
        for (int t = 0; t < 2; t++) {
            int lx = w + t*4;
            int r = lx*8 + sr;
            int cbs = scb ^ ((r & 7) << 4);
            GLDS(kbase + (size_t)(kv0 + r)*3*DM*2 + cbs, K_lds[slot] + lx*1024);
            GLDS(vtbase + (size_t)r*TT*2 + kv0*2 + cbs, VT_lds[slot] + lx*1024);
        }
    };

    STAGE(0, 0);
    STAGE(1, 1 <= qt ? 1 : qt);
    for (int kt = 0; kt <= qt; ++kt) {
        int cur = kt % 3;
        STAGE((kt+2) % 3, kt+2 <= qt ? kt+2 : qt);   // always-stage (clamped)
        __builtin_amdgcn_sched_barrier(0);
        asm volatile("s_waitcnt vmcnt(8)" ::: "memory");   // tile kt landed
        __builtin_amdgcn_s_barrier();
        __builtin_amdgcn_sched_barrier(0);

        f32x4 st[4] = {};
        #pragma unroll
        for (int t = 0; t < 4; ++t) {
            #pragma unroll
            for (int ks = 0; ks < 2; ++ks) {
                int row = t*16 + lr;
                bf16x8 kf = *(const bf16x8*)(K_lds[cur] + row*128 + ((ks*64 + kq*16) ^ ((lr&7)<<4)));
                st[t] = __builtin_amdgcn_mfma_f32_16x16x32_bf16(kf, qfrag[ks], st[t], 0,0,0);
            }
        }

        float sv[4][4];
        bool diag = (kt == qt);
        float pmax = -INFINITY;
        #pragma unroll
        for (int t = 0; t < 4; ++t)
            #pragma unroll
            for (int jj = 0; jj < 4; ++jj) {
                float s = st[t][jj] * scale;
                if (diag && (t*16 + kq*4 + jj > w*16 + lr)) s = -INFINITY;
                sv[t][jj] = s;
                pmax = fmaxf(pmax, s);
            }
        pmax = fmaxf(pmax, __shfl_xor(pmax, 16));
        pmax = fmaxf(pmax, __shfl_xor(pmax, 32));
        float m_new = fmaxf(m_run, pmax);
        float corr = __expf(m_run - m_new);
        float rsum = 0.f;
        #pragma unroll
        for (int t = 0; t < 4; ++t)
            #pragma unroll
            for (int jj = 0; jj < 4; ++jj) {
                float p = __expf(sv[t][jj] - m_new);
                sv[t][jj] = p;
                rsum += p;
            }
        rsum += __shfl_xor(rsum, 16);
        rsum += __shfl_xor(rsum, 32);
        l_run = l_run * corr + rsum;
        m_run = m_new;

        #pragma unroll
        for (int jj = 0; jj < 4; ++jj) {
            float c = __shfl(corr, kq*20 + jj);
            #pragma unroll
            for (int nt = 0; nt < 4; ++nt) oacc[nt][jj] *= c;
        }

        #pragma unroll
        for (int t = 0; t < 4; ++t) {
            unsigned pk0 = (unsigned)f2bf(sv[t][0]) | ((unsigned)f2bf(sv[t][1]) << 16);
            unsigned pk1 = (unsigned)f2bf(sv[t][2]) | ((unsigned)f2bf(sv[t][3]) << 16);
            unsigned off = ((unsigned)(lr*128 + t*32 + kq*8)) ^ (((unsigned)lr&7u)<<4);
            *(uint2*)(P_lds[w] + off) = make_uint2(pk0, pk1);
        }

        #pragma unroll
        for (int ks = 0; ks < 2; ++ks) {
            bf16x8 pa = *(const bf16x8*)(P_lds[w] +
                ((unsigned)(lr*128 + ((ks*64 + kq*16) ^ ((lr&7)<<4)))));
            #pragma unroll
            for (int nt = 0; nt < 4; ++nt) {
                int row = nt*16 + lr;
                bf16x8 vf = *(const bf16x8*)(VT_lds[cur] + row*128 + ((ks*64 + kq*16) ^ ((lr&7)<<4)));
                oacc[nt] = __builtin_amdgcn_mfma_f32_16x16x32_bf16(pa, vf, oacc[nt], 0,0,0);
            }
        }

        __builtin_amdgcn_sched_barrier(0);
        asm volatile("s_waitcnt lgkmcnt(0)" ::: "memory");
        __builtin_amdgcn_s_barrier();             // WAR: slot reused next iter
    }

    #pragma unroll
    for (int jj = 0; jj < 4; ++jj) {
        float li = __shfl(l_run, kq*20 + jj);
        int qg = q0 + w*16 + kq*4 + jj;
        #pragma unroll
        for (int nt = 0; nt < 4; ++nt)
            y[(size_t)(b*TT + qg)*DM + h*64 + nt*16 + lr] =
                __float2bfloat16(oacc[nt][jj] / li);
    }
}

// ---------------- loss from fused partials: one wave per row ----------------
__global__ void zero_acc_kernel(float* p) { p[threadIdx.x] = 0.f; }

__global__ __launch_bounds__(64) void loss_reduce_kernel(const float* __restrict__ part,
                                                         const float* __restrict__ logits,
                                                         const int* __restrict__ targets,
                                                         float* __restrict__ acc) {
    int row = blockIdx.x;
    int lane = threadIdx.x;
    const int nbx = (VOC + 127) >> 7;   // 393
    float m = -INFINITY, s = 0.f;
    for (int bx = lane; bx < nbx; bx += 64) {
        float2 p = ((const float2*)part)[(size_t)row*nbx + bx];
        float Mx = fmaxf(m, p.x);
        s = s*__expf(m - Mx) + p.y*__expf(p.x - Mx);
        m = Mx;
    }
    #pragma unroll
    for (int off = 32; off > 0; off >>= 1) {
        float m2 = __shfl_xor(m, off), s2 = __shfl_xor(s, off);
        float Mx = fmaxf(m, m2);
        s = s*__expf(m - Mx) + s2*__expf(m2 - Mx);
        m = Mx;
    }
    if (lane == 0) {
        int tgt = targets[row];
        if (tgt >= 0) {
            float lse = logf(s) + m;
            atomicAdd(&acc[0], lse - logits[(size_t)row*VOC + tgt]);
            atomicAdd(&acc[1], 1.f);
        }
    }
}

__global__ void loss_final_kernel(const float* acc, float* out) {
    out[0] = acc[0] / acc[1];
}

// ---------------- launch ----------------
static inline TJob mkjob(const float* in, __hip_bfloat16* out, int R, int C, int tile0) {
    TJob j; j.in = in; j.out = out; j.R = R; j.C = C;
    j.cx = (C + 31)/32; j.tile0 = tile0;
    return j;
}

extern "C" void kernel_launch(void* const* d_in, const int* in_sizes, int n_in,
                              void* d_out, int out_size, void* d_ws, size_t ws_size,
                              hipStream_t stream) {
    const int*   idx     = (const int*)  d_in[0];
    const int*   targets = (const int*)  d_in[1];
    const float* wte     = (const float*)d_in[2];
    const float* wpe     = (const float*)d_in[3];
    const float* ln1_g   = (const float*)d_in[4];
    const float* ln1_b   = (const float*)d_in[5];
    const float* qkv_w   = (const float*)d_in[6];
    const float* qkv_b   = (const float*)d_in[7];
    const float* po_w    = (const float*)d_in[8];
    const float* po_b    = (const float*)d_in[9];
    const float* ln2_g   = (const float*)d_in[10];
    const float* ln2_b   = (const float*)d_in[11];
    const float* fc_w    = (const float*)d_in[12];
    const float* fc_b    = (const float*)d_in[13];
    const float* pr_w    = (const float*)d_in[14];
    const float* pr_b    = (const float*)d_in[15];
    const float* lnf_g   = (const float*)d_in[16];
    const float* lnf_b   = (const float*)d_in[17];
    const float* lm_w    = (const float*)d_in[18];

    float* logits = (float*)d_out;                 // [MR][VOC], loss appended

    char* p = (char*)d_ws;
    float* x = (float*)p;                 p += (size_t)MR*DM*4;
    __hip_bfloat16* h    = (__hip_bfloat16*)p; p += (size_t)MR*DM*2;
    __hip_bfloat16* qkvb = (__hip_bfloat16*)p; p += (size_t)MR*3*DM*2;
    __hip_bfloat16* yb   = (__hip_bfloat16*)p; p += (size_t)MR*DM*2;
    __hip_bfloat16* fb   = (__hip_bfloat16*)p; p += (size_t)MR*FF*2;
    __hip_bfloat16* vtb  = (__hip_bfloat16*)p; p += (size_t)BB*NH*64*TT*2;
    __hip_bfloat16* lm_wt  = (__hip_bfloat16*)p; p += (size_t)VOC*DM*2;
    __hip_bfloat16* qkv_wt = (__hip_bfloat16*)p; p += (size_t)3*DM*DM*2;
    __hip_bfloat16* po_wt  = (__hip_bfloat16*)p; p += (size_t)DM*DM*2;
    __hip_bfloat16* fc_wt  = (__hip_bfloat16*)p; p += (size_t)FF*DM*2;
    __hip_bfloat16* pr_wt  = (__hip_bfloat16*)p; p += (size_t)DM*FF*2;
    float* part = (float*)p;              p += (size_t)MR*((VOC+127)/128)*2*4;
    float* lacc = (float*)p;

    dim3 tpb(32, 8);

    embed_kernel<<<MR, 256, 0, stream>>>(idx, wte, wpe, x);

    {
        TJob j = mkjob(lm_w, lm_wt, DM, VOC, 0);
        int tiles = j.cx * ((DM+31)/32);
        trans1_kernel<<<tiles, tpb, 0, stream>>>(j);
    }

    for (int l = 0; l < NL; l++) {
        TJob j0 = mkjob(qkv_w + (size_t)l*DM*3*DM, qkv_wt, DM, 3*DM, 0);
        int t1 = j0.cx * 24;
        TJob j1 = mkjob(po_w + (size_t)l*DM*DM, po_wt, DM, DM, t1);
        int t2 = t1 + j1.cx * 24;
        TJob j2 = mkjob(fc_w + (size_t)l*DM*FF, fc_wt, DM, FF, t2);
        int t3 = t2 + j2.cx * 24;
        TJob j3 = mkjob(pr_w + (size_t)l*FF*DM, pr_wt, FF, DM, t3);
        int tot = t3 + j3.cx * 96;
        trans4_kernel<<<tot, tpb, 0, stream>>>(j0, j1, j2, j3);

        ln_kernel<<<MR/4, 256, 0, stream>>>(x, ln1_g + l*DM, ln1_b + l*DM, h);
        mfma_gemm_kernel<1,0><<<(3*DM/128)*(MR/128), 256, 0, stream>>>(
            h, qkv_wt, qkv_b + (size_t)l*3*DM, nullptr, qkvb, vtb, nullptr, MR, 3*DM, DM);
        mfma_attn_kernel<<<BB*NH*(TT/64), 256, 0, stream>>>(qkvb, vtb, yb);
        mfma_gemm_kernel<2,1><<<(DM/128)*(MR/64), 256, 0, stream>>>(
            yb, po_wt, po_b + (size_t)l*DM, x, x, nullptr, nullptr, MR, DM, DM);
        ln_kernel<<<MR/4, 256, 0, stream>>>(x, ln2_g + l*DM, ln2_b + l*DM, h);
        mfma_gemm_kernel<3,0><<<(FF/128)*(MR/128), 256, 0, stream>>>(
            h, fc_wt, fc_b + (size_t)l*FF, nullptr, fb, nullptr, nullptr, MR, FF, DM);
        mfma_gemm_kernel<2,1><<<(DM/128)*(MR/64), 256, 0, stream>>>(
            fb, pr_wt, pr_b + (size_t)l*DM, x, x, nullptr, nullptr, MR, DM, FF);
    }

    ln_kernel<<<MR/4, 256, 0, stream>>>(x, lnf_g, lnf_b, h);
    mfma_gemm_kernel<0,0><<<((VOC+127)/128)*(MR/128), 256, 0, stream>>>(
        h, lm_wt, nullptr, nullptr, logits, nullptr, part, MR, VOC, DM);

    zero_acc_kernel<<<1, 2, 0, stream>>>(lacc);
    loss_reduce_kernel<<<MR, 64, 0, stream>>>(part, logits, targets, lacc);
    loss_final_kernel<<<1, 1, 0, stream>>>(lacc, logits + (size_t)MR*VOC);
}

// Round 18
// 2849.528 us; speedup vs baseline: 1.0910x; 1.0037x over previous
//
#include <hip/hip_runtime.h>
#include <hip/hip_bf16.h>
#include <math.h>

#define VOC 50257
#define NL 12
#define NH 12
#define DM 768
#define FF 3072
#define BB 2
#define TT 1024
#define MR (BB*TT)   // 2048 rows

typedef __attribute__((ext_vector_type(8))) short bf16x8;
typedef __attribute__((ext_vector_type(4))) float f32x4;

__device__ __forceinline__ float mgelu_f(float x) {
    return 0.5f*x*(1.f + tanhf(0.7978845608028654f*(x + 0.047715f*x*x*x)));
}

__device__ __forceinline__ unsigned short f2bf(float f) {
    __hip_bfloat16 h = __float2bfloat16(f);
    return *reinterpret_cast<unsigned short*>(&h);
}

#define GLDS(gptr, lptr) __builtin_amdgcn_global_load_lds( \
    (const __attribute__((address_space(1))) void*)(gptr), \
    (__attribute__((address_space(3))) void*)(lptr), 16, 0, 0)

// XCD-chunked bijective remap (m204)
__device__ __forceinline__ int xcd_work(int bid, int total) {
    int xcd = bid & 7;
    int seq = bid >> 3;
    int q = total >> 3, r = total & 7;
    int base = (xcd < r) ? xcd*(q+1) : r + xcd*q;
    return base + seq;
}

// ---------------- embedding ----------------
__global__ void embed_kernel(const int* __restrict__ idx, const float* __restrict__ wte,
                             const float* __restrict__ wpe, float* __restrict__ x) {
    int row = blockIdx.x;
    int t = row % TT;
    int tok = idx[row];
    for (int d = threadIdx.x; d < DM; d += blockDim.x)
        x[(size_t)row*DM + d] = wte[(size_t)tok*DM + d] + wpe[(size_t)t*DM + d];
}

// ---------------- layernorm: 4 rows/block (one wave each) ----------------
__global__ __launch_bounds__(256) void ln_kernel(const float* __restrict__ x,
                          const float* __restrict__ g,
                          const float* __restrict__ b, __hip_bfloat16* __restrict__ out) {
    int row = blockIdx.x*4 + (threadIdx.x >> 6);
    int lane = threadIdx.x & 63;
    const float* xr = x + (size_t)row*DM;
    float vals[DM/64];
    float s = 0.f;
    #pragma unroll
    for (int i = 0; i < DM/64; i++) { vals[i] = xr[lane + i*64]; s += vals[i]; }
    #pragma unroll
    for (int off = 32; off > 0; off >>= 1) s += __shfl_xor(s, off);
    float mean = s * (1.0f/DM);
    float vs = 0.f;
    #pragma unroll
    for (int i = 0; i < DM/64; i++) { float d = vals[i]-mean; vs += d*d; }
    #pragma unroll
    for (int off = 32; off > 0; off >>= 1) vs += __shfl_xor(vs, off);
    float rstd = rsqrtf(vs * (1.0f/DM) + 1e-5f);
    #pragma unroll
    for (int i = 0; i < DM/64; i++) {
        int d = lane + i*64;
        out[(size_t)row*DM + d] = __float2bfloat16((vals[i]-mean)*rstd*g[d] + b[d]);
    }
}

// ---------------- fused 4x transpose+cvt (per-layer, keeps weights L2-hot) ----------------
struct TJob { const float* in; __hip_bfloat16* out; int R, C, cx, tile0; };

__device__ __forceinline__ void trans_one(const TJob& j, int t) {
    __shared__ float tile[32][33];
    int bx = t % j.cx, by = t / j.cx;
    int c0 = bx*32, r0 = by*32;
    int tx = threadIdx.x, ty = threadIdx.y;   // 32 x 8
    #pragma unroll
    for (int i = ty; i < 32; i += 8) {
        int r = r0 + i, c = c0 + tx;
        tile[i][tx] = (r < j.R && c < j.C) ? j.in[(size_t)r*j.C + c] : 0.f;
    }
    __syncthreads();
    #pragma unroll
    for (int i = ty; i < 32; i += 8) {
        int c = c0 + i, r = r0 + tx;
        if (c < j.C && r < j.R) j.out[(size_t)c*j.R + r] = __float2bfloat16(tile[tx][i]);
    }
}

__global__ void trans4_kernel(TJob j0, TJob j1, TJob j2, TJob j3) {
    int t = blockIdx.x;
    if (t >= j3.tile0)      trans_one(j3, t - j3.tile0);
    else if (t >= j2.tile0) trans_one(j2, t - j2.tile0);
    else if (t >= j1.tile0) trans_one(j1, t - j1.tile0);
    else                    trans_one(j0, t);
}

__global__ void trans1_kernel(TJob j0) { trans_one(j0, blockIdx.x); }

// ---------------- MFMA bf16 GEMM, 3-slot ring + counted vmcnt (T3/T4), no setprio ----------------
// TILE: 0 = 128x128 (2x2 waves, 4x4); 1 = 64x128 (1x4 waves, 4x2)
// MODE: 0 = f32 out coalesced + fused LSE partials (TILE0); 1 = bf16+bias (+V^T);
//       2 = f32+bias+res; 3 = bf16 gelu+bias
template<int MODE, int TILE>
__global__ __launch_bounds__(256) void mfma_gemm_kernel(
        const __hip_bfloat16* __restrict__ A,
        const __hip_bfloat16* __restrict__ Wt,
        const float* __restrict__ bias,
        const float* __restrict__ res,
        void* __restrict__ Cout,
        __hip_bfloat16* __restrict__ vt,
        float* __restrict__ part,
        int M, int N, int K) {
    constexpr int BM  = (TILE == 1) ? 64 : 128;
    constexpr int MF  = 4;
    constexpr int NF  = (TILE == 0) ? 4 : 2;
    constexpr int ABM = BM*64;                    // one A slot
    constexpr int RING = 3*ABM + 3*8192;
    constexpr int SMEMB = (MODE == 0 && RING < 34816) ? 34816 : RING;  // eps overlay
    __shared__ __align__(16) char smem[SMEMB];
    char* As = smem;
    char* Bs = smem + 3*ABM;
    int tid = threadIdx.x;
    int lane = tid & 63, wid = tid >> 6;
    int kq = lane >> 4, lr = lane & 15;

    int nby = M / BM;
    int work = xcd_work(blockIdx.x, gridDim.x);
    int by = work % nby;          // M-tile inner: consecutive works share W panel
    int bx = work / nby;
    int m0 = by * BM, n0 = bx * 128;

    int wm = (TILE == 1) ? 0 : (wid >> 1);
    int wn = (TILE == 1) ? wid : (wid & 1);
    int colbase = (TILE == 0) ? wn*64 : wn*32;

    f32x4 acc[MF][NF] = {};

    auto STAGE = [&](int slot, int k0) {
        if constexpr (TILE == 0) {
            #pragma unroll
            for (int t = 0; t < 2; t++) {
                int lx = wid + t*4;
                int r  = (lx & 1)*64 + lane;
                int kk = (lx >> 1)*8;
                GLDS(A + (size_t)(m0 + r)*K + k0 + kk, As + slot*ABM + lx*1024);
                int nr = n0 + r; if (nr > N-1) nr = N-1;
                GLDS(Wt + (size_t)nr*K + k0 + kk, Bs + slot*8192 + lx*1024);
            }
        } else {
            GLDS(A + (size_t)(m0 + lane)*K + k0 + wid*8, As + slot*ABM + wid*1024);
            #pragma unroll
            for (int t = 0; t < 2; t++) {
                int lx = wid + t*4;
                int r  = (lx & 1)*64 + lane;
                int kk = (lx >> 1)*8;
                int nr = n0 + r; if (nr > N-1) nr = N-1;
                GLDS(Wt + (size_t)nr*K + k0 + kk, Bs + slot*8192 + lx*1024);
            }
        }
    };

    int nk = K >> 5;
    STAGE(0, 0);
    STAGE(1, (1 < nk ? 1 : nk-1)*32);
    for (int ki = 0; ki < nk; ++ki) {
        int cur = ki % 3;
        int k2 = (ki+2 < nk ? ki+2 : nk-1)*32;    // always-stage (clamped) -> const vmcnt
        STAGE((ki+2) % 3, k2);
        __builtin_amdgcn_sched_barrier(0);
        // tiles ki+1, ki+2 stay in flight; everything older (incl. tile ki) drained
        if constexpr (TILE == 0) asm volatile("s_waitcnt vmcnt(8)" ::: "memory");
        else                     asm volatile("s_waitcnt vmcnt(6)" ::: "memory");
        __builtin_amdgcn_s_barrier();             // tile ki visible to all waves
        __builtin_amdgcn_sched_barrier(0);

        bf16x8 afrag[MF], bfrag[NF];
        #pragma unroll
        for (int m = 0; m < MF; m++)
            afrag[m] = *(const bf16x8*)(As + cur*ABM + kq*(BM*16) + (wm*64 + m*16 + lr)*16);
        #pragma unroll
        for (int n = 0; n < NF; n++)
            bfrag[n] = *(const bf16x8*)(Bs + cur*8192 + kq*2048 + (colbase + n*16 + lr)*16);
        #pragma unroll
        for (int m = 0; m < MF; m++)
            #pragma unroll
            for (int n = 0; n < NF; n++)
                acc[m][n] = __builtin_amdgcn_mfma_f32_16x16x32_bf16(afrag[m], bfrag[n], acc[m][n], 0, 0, 0);

        __builtin_amdgcn_sched_barrier(0);
        asm volatile("s_waitcnt lgkmcnt(0)" ::: "memory");
        __builtin_amdgcn_s_barrier();             // WAR: slot reused by next iter's STAGE
    }

    if constexpr (MODE == 0) {
        // ---- coalesced epilogue (normal stores; L2-writeback full lines) + fused LSE partials
        float* eps = (float*)smem;            // [128 rows][68 cols] f32 (stride-68)
        int nbx = (N + 127) >> 7;
        int rl2 = tid >> 1, sub = tid & 1;    // LSE ownership: thread pair per row
        float pm = -INFINITY, ps = 0.f;
        #pragma unroll
        for (int hh = 0; hh < 2; ++hh) {
            __syncthreads();                  // drains vmcnt(0): leftover ring stages landed
            if (wn == hh) {
                #pragma unroll
                for (int m = 0; m < 4; m++)
                    #pragma unroll
                    for (int n = 0; n < 4; n++) {
                        int cl = n*16 + lr;
                        #pragma unroll
                        for (int j = 0; j < 4; j++)
                            eps[(wm*64 + m*16 + kq*4 + j)*68 + cl] = acc[m][n][j];
                    }
            }
            __syncthreads();
            // full-line stores: 16 lanes x f32x4 = 256B dense per row
            #pragma unroll
            for (int it = 0; it < 8; ++it) {
                int rl = it*16 + (tid >> 4);
                int c4 = tid & 15;
                int col = n0 + hh*64 + c4*4;
                int row = m0 + rl;
                f32x4 v = *(const f32x4*)(eps + rl*68 + c4*4);
                if (col + 3 < N) {
                    *(f32x4*)&((float*)Cout)[(size_t)row*N + col] = v;
                } else {
                    #pragma unroll
                    for (int u = 0; u < 4; ++u)
                        if (col + u < N) ((float*)Cout)[(size_t)row*N + col + u] = v[u];
                }
            }
            // branch-free 2-pass LSE over this half's 32 cols per thread
            float hm = -INFINITY;
            #pragma unroll
            for (int i = 0; i < 8; ++i) {
                f32x4 v = *(const f32x4*)(eps + rl2*68 + sub*32 + i*4);
                #pragma unroll
                for (int u = 0; u < 4; ++u) {
                    int col = n0 + hh*64 + sub*32 + i*4 + u;
                    hm = fmaxf(hm, (col < N) ? v[u] : -INFINITY);
                }
            }
            float nm = fmaxf(pm, hm);
            ps *= __expf(pm - nm);
            pm = nm;
            #pragma unroll
            for (int i = 0; i < 8; ++i) {
                f32x4 v = *(const f32x4*)(eps + rl2*68 + sub*32 + i*4);
                #pragma unroll
                for (int u = 0; u < 4; ++u) {
                    int col = n0 + hh*64 + sub*32 + i*4 + u;
                    ps += __expf(((col < N) ? v[u] : -INFINITY) - pm);
                }
            }
        }
        float m2 = __shfl_xor(pm, 1), s2 = __shfl_xor(ps, 1);
        float Mx = fmaxf(pm, m2);
        float Sx = ps*__expf(pm - Mx) + s2*__expf(m2 - Mx);
        if (sub == 0)
            ((float2*)part)[(size_t)(m0 + rl2)*nbx + bx] = make_float2(Mx, Sx);
        return;
    }

    #pragma unroll
    for (int m = 0; m < MF; m++) {
        #pragma unroll
        for (int n = 0; n < NF; n++) {
            int col = n0 + colbase + n*16 + lr;
            if (col >= N) continue;
            float bv = bias[col];
            #pragma unroll
            for (int j = 0; j < 4; j++) {
                int row = m0 + wm*64 + m*16 + kq*4 + j;
                float v = acc[m][n][j] + bv;
                size_t o = (size_t)row*N + col;
                if (MODE == 1) {
                    __hip_bfloat16 bvv = __float2bfloat16(v);
                    ((__hip_bfloat16*)Cout)[o] = bvv;
                    if (col >= 2*DM) {   // V columns -> also write V^T [b*NH+h][d][t]
                        int hh = (col - 2*DM) >> 6, dd = (col - 2*DM) & 63;
                        int bb = row >> 10, tt = row & 1023;
                        vt[(((size_t)bb*NH + hh)*64 + dd)*TT + tt] = bvv;
                    }
                } else if (MODE == 2) {
                    ((float*)Cout)[o] = v + res[o];
                } else {
                    ((__hip_bfloat16*)Cout)[o] = __float2bfloat16(mgelu_f(v));
                }
            }
        }
    }
}

// ---------------- MFMA flash attention, 3-slot ring + counted vmcnt (r11 form) ----------------
__global__ __launch_bounds__(256) void mfma_attn_kernel(const __hip_bfloat16* __restrict__ qkv,
                                                        const __hip_bfloat16* __restrict__ vt,
                                                        __hip_bfloat16* __restrict__ y) {
    __shared__ __align__(16) char K_lds[3][8192];     // [64 kv][128B d], byte ^ ((kv&7)<<4)
    __shared__ __align__(16) char VT_lds[3][8192];    // [64 d][128B kv], byte ^ ((d&7)<<4)
    __shared__ __align__(16) char P_lds[4][2048];     // per-wave [16 q][128B kv], ^ ((q&7)<<4)

    int work = xcd_work(blockIdx.x, BB*NH*16);
    int qt = 15 - (work & 15);            // LPT: heaviest q-tiles first
    int bh = work >> 4;
    int h  = bh % NH;
    int b  = bh / NH;
    int tid = threadIdx.x;
    int lane = tid & 63, w = tid >> 6;
    int lr = lane & 15, kq = lane >> 4;
    int q0 = qt * 64;

    int sr = lane >> 3;                   // staging row-within-chunk
    int scb = (lane & 7) * 16;            // staging colByte

    int qrow = q0 + w*16 + lr;
    const __hip_bfloat16* qp = qkv + (size_t)(b*TT + qrow)*3*DM + h*64;
    bf16x8 qfrag[2];
    qfrag[0] = *(const bf16x8*)(qp + kq*8);
    qfrag[1] = *(const bf16x8*)(qp + 32 + kq*8);

    f32x4 oacc[4] = {};
    float m_run = -INFINITY, l_run = 0.f;
    const float scale = 0.125f;

    const char* kbase  = (const char*)qkv + ((size_t)b*TT*3*DM + DM + h*64)*2;
    const char* vtbase = (const char*)vt + ((size_t)(b*NH + h)*64)*TT*2;

    auto STAGE = [&](int slot, int kt) {
        int kv0 = kt*64;
        #pragma unroll
        for (int t = 0; t < 2; t++) {
            int lx = w + t*4;
            int r = lx*8 + sr;
            int cbs = scb ^ ((r & 7) << 4);
            GLDS(kbase + (size_t)(kv0 + r)*3*DM*2 + cbs, K_lds[slot] + lx*1024);
            GLDS(vtbase + (size_t)r*TT*2 + kv0*2 + cbs, VT_lds[slot] + lx*1024);
        }
    };

    STAGE(0, 0);
    STAGE(1, 1 <= qt ? 1 : qt);
    for (int kt = 0; kt <= qt; ++kt) {
        int cur = kt % 3;
        STAGE((kt+2) % 3, kt+2 <= qt ? kt+2 : qt);   // always-stage (clamped)
        __builtin_amdgcn_sched_barrier(0);
        asm volatile("s_waitcnt vmcnt(8)" ::: "memory");   // tile kt landed
        __builtin_amdgcn_s_barrier();
        __builtin_amdgcn_sched_barrier(0);

        f32x4 st[4] = {};
        #pragma unroll
        for (int t = 0; t < 4; ++t) {
            #pragma unroll
            for (int ks = 0; ks < 2; ++ks) {
                int row = t*16 + lr;
                bf16x8 kf = *(const bf16x8*)(K_lds[cur] + row*128 + ((ks*64 + kq*16) ^ ((lr&7)<<4)));
                st[t] = __builtin_amdgcn_mfma_f32_16x16x32_bf16(kf, qfrag[ks], st[t], 0,0,0);
            }
        }

        float sv[4][4];
        bool diag = (kt == qt);
        float pmax = -INFINITY;
        #pragma unroll
        for (int t = 0; t < 4; ++t)
            #pragma unroll
            for (int jj = 0; jj < 4; ++jj) {
                float s = st[t][jj] * scale;
                if (diag && (t*16 + kq*4 + jj > w*16 + lr)) s = -INFINITY;
                sv[t][jj] = s;
                pmax = fmaxf(pmax, s);
            }
        pmax = fmaxf(pmax, __shfl_xor(pmax, 16));
        pmax = fmaxf(pmax, __shfl_xor(pmax, 32));
        float m_new = fmaxf(m_run, pmax);
        float corr = __expf(m_run - m_new);
        float rsum = 0.f;
        #pragma unroll
        for (int t = 0; t < 4; ++t)
            #pragma unroll
            for (int jj = 0; jj < 4; ++jj) {
                float p = __expf(sv[t][jj] - m_new);
                sv[t][jj] = p;
                rsum += p;
            }
        rsum += __shfl_xor(rsum, 16);
        rsum += __shfl_xor(rsum, 32);
        l_run = l_run * corr + rsum;
        m_run = m_new;

        #pragma unroll
        for (int jj = 0; jj < 4; ++jj) {
            float c = __shfl(corr, kq*20 + jj);
            #pragma unroll
            for (int nt = 0; nt < 4; ++nt) oacc[nt][jj] *= c;
        }

        #pragma unroll
        for (int t = 0; t < 4; ++t) {
            unsigned pk0 = (unsigned)f2bf(sv[t][0]) | ((unsigned)f2bf(sv[t][1]) << 16);
            unsigned pk1 = (unsigned)f2bf(sv[t][2]) | ((unsigned)f2bf(sv[t][3]) << 16);
            unsigned off = ((unsigned)(lr*128 + t*32 + kq*8)) ^ (((unsigned)lr&7u)<<4);
            *(uint2*)(P_lds[w] + off) = make_uint2(pk0, pk1);
        }

        #pragma unroll
        for (int ks = 0; ks < 2; ++ks) {
            bf16x8 pa = *(const bf16x8*)(P_lds[w] +
                ((unsigned)(lr*128 + ((ks*64 + kq*16) ^ ((lr&7)<<4)))));
            #pragma unroll
            for (int nt = 0; nt < 4; ++nt) {
                int row = nt*16 + lr;
                bf16x8 vf = *(const bf16x8*)(VT_lds[cur] + row*128 + ((ks*64 + kq*16) ^ ((lr&7)<<4)));
                oacc[nt] = __builtin_amdgcn_mfma_f32_16x16x32_bf16(pa, vf, oacc[nt], 0,0,0);
            }
        }

        __builtin_amdgcn_sched_barrier(0);
        asm volatile("s_waitcnt lgkmcnt(0)" ::: "memory");
        __builtin_amdgcn_s_barrier();             // WAR: slot reused next iter
    }

    #pragma unroll
    for (int jj = 0; jj < 4; ++jj) {
        float li = __shfl(l_run, kq*20 + jj);
        int qg = q0 + w*16 + kq*4 + jj;
        #pragma unroll
        for (int nt = 0; nt < 4; ++nt)
            y[(size_t)(b*TT + qg)*DM + h*64 + nt*16 + lr] =
                __float2bfloat16(oacc[nt][jj] / li);
    }
}

// ---------------- loss from fused partials: one wave per row ----------------
__global__ void zero_acc_kernel(float* p) { p[threadIdx.x] = 0.f; }

__global__ __launch_bounds__(64) void loss_reduce_kernel(const float* __restrict__ part,
                                                         const float* __restrict__ logits,
                                                         const int* __restrict__ targets,
                                                         float* __restrict__ acc) {
    int row = blockIdx.x;
    int lane = threadIdx.x;
    const int nbx = (VOC + 127) >> 7;   // 393
    float m = -INFINITY, s = 0.f;
    for (int bx = lane; bx < nbx; bx += 64) {
        float2 p = ((const float2*)part)[(size_t)row*nbx + bx];
        float Mx = fmaxf(m, p.x);
        s = s*__expf(m - Mx) + p.y*__expf(p.x - Mx);
        m = Mx;
    }
    #pragma unroll
    for (int off = 32; off > 0; off >>= 1) {
        float m2 = __shfl_xor(m, off), s2 = __shfl_xor(s, off);
        float Mx = fmaxf(m, m2);
        s = s*__expf(m - Mx) + s2*__expf(m2 - Mx);
        m = Mx;
    }
    if (lane == 0) {
        int tgt = targets[row];
        if (tgt >= 0) {
            float lse = logf(s) + m;
            atomicAdd(&acc[0], lse - logits[(size_t)row*VOC + tgt]);
            atomicAdd(&acc[1], 1.f);
        }
    }
}

__global__ void loss_final_kernel(const float* acc, float* out) {
    out[0] = acc[0] / acc[1];
}

// ---------------- launch ----------------
static inline TJob mkjob(const float* in, __hip_bfloat16* out, int R, int C, int tile0) {
    TJob j; j.in = in; j.out = out; j.R = R; j.C = C;
    j.cx = (C + 31)/32; j.tile0 = tile0;
    return j;
}

extern "C" void kernel_launch(void* const* d_in, const int* in_sizes, int n_in,
                              void* d_out, int out_size, void* d_ws, size_t ws_size,
                              hipStream_t stream) {
    const int*   idx     = (const int*)  d_in[0];
    const int*   targets = (const int*)  d_in[1];
    const float* wte     = (const float*)d_in[2];
    const float* wpe     = (const float*)d_in[3];
    const float* ln1_g   = (const float*)d_in[4];
    const float* ln1_b   = (const float*)d_in[5];
    const float* qkv_w   = (const float*)d_in[6];
    const float* qkv_b   = (const float*)d_in[7];
    const float* po_w    = (const float*)d_in[8];
    const float* po_b    = (const float*)d_in[9];
    const float* ln2_g   = (const float*)d_in[10];
    const float* ln2_b   = (const float*)d_in[11];
    const float* fc_w    = (const float*)d_in[12];
    const float* fc_b    = (const float*)d_in[13];
    const float* pr_w    = (const float*)d_in[14];
    const float* pr_b    = (const float*)d_in[15];
    const float* lnf_g   = (const float*)d_in[16];
    const float* lnf_b   = (const float*)d_in[17];
    const float* lm_w    = (const float*)d_in[18];

    float* logits = (float*)d_out;                 // [MR][VOC], loss appended

    char* p = (char*)d_ws;
    float* x = (float*)p;                 p += (size_t)MR*DM*4;
    __hip_bfloat16* h    = (__hip_bfloat16*)p; p += (size_t)MR*DM*2;
    __hip_bfloat16* qkvb = (__hip_bfloat16*)p; p += (size_t)MR*3*DM*2;
    __hip_bfloat16* yb   = (__hip_bfloat16*)p; p += (size_t)MR*DM*2;
    __hip_bfloat16* fb   = (__hip_bfloat16*)p; p += (size_t)MR*FF*2;
    __hip_bfloat16* vtb  = (__hip_bfloat16*)p; p += (size_t)BB*NH*64*TT*2;
    __hip_bfloat16* lm_wt  = (__hip_bfloat16*)p; p += (size_t)VOC*DM*2;
    __hip_bfloat16* qkv_wt = (__hip_bfloat16*)p; p += (size_t)3*DM*DM*2;
    __hip_bfloat16* po_wt  = (__hip_bfloat16*)p; p += (size_t)DM*DM*2;
    __hip_bfloat16* fc_wt  = (__hip_bfloat16*)p; p += (size_t)FF*DM*2;
    __hip_bfloat16* pr_wt  = (__hip_bfloat16*)p; p += (size_t)DM*FF*2;
    float* part = (float*)p;              p += (size_t)MR*((VOC+127)/128)*2*4;
    float* lacc = (float*)p;

    dim3 tpb(32, 8);

    embed_kernel<<<MR, 256, 0, stream>>>(idx, wte, wpe, x);

    {
        TJob j = mkjob(lm_w, lm_wt, DM, VOC, 0);
        int tiles = j.cx * ((DM+31)/32);
        trans1_kernel<<<tiles, tpb, 0, stream>>>(j);
    }

    for (int l = 0; l < NL; l++) {
        TJob j0 = mkjob(qkv_w + (size_t)l*DM*3*DM, qkv_wt, DM, 3*DM, 0);
        int t1 = j0.cx * 24;
        TJob j1 = mkjob(po_w + (size_t)l*DM*DM, po_wt, DM, DM, t1);
        int t2 = t1 + j1.cx * 24;
        TJob j2 = mkjob(fc_w + (size_t)l*DM*FF, fc_wt, DM, FF, t2);
        int t3 = t2 + j2.cx * 24;
        TJob j3 = mkjob(pr_w + (size_t)l*FF*DM, pr_wt, FF, DM, t3);
        int tot = t3 + j3.cx * 96;
        trans4_kernel<<<tot, tpb, 0, stream>>>(j0, j1, j2, j3);

        ln_kernel<<<MR/4, 256, 0, stream>>>(x, ln1_g + l*DM, ln1_b + l*DM, h);
        mfma_gemm_kernel<1,0><<<(3*DM/128)*(MR/128), 256, 0, stream>>>(
            h, qkv_wt, qkv_b + (size_t)l*3*DM, nullptr, qkvb, vtb, nullptr, MR, 3*DM, DM);
        mfma_attn_kernel<<<BB*NH*(TT/64), 256, 0, stream>>>(qkvb, vtb, yb);
        mfma_gemm_kernel<2,1><<<(DM/128)*(MR/64), 256, 0, stream>>>(
            yb, po_wt, po_b + (size_t)l*DM, x, x, nullptr, nullptr, MR, DM, DM);
        ln_kernel<<<MR/4, 256, 0, stream>>>(x, ln2_g + l*DM, ln2_b + l*DM, h);
        mfma_gemm_kernel<3,0><<<(FF/128)*(MR/128), 256, 0, stream>>>(
            h, fc_wt, fc_b + (size_t)l*FF, nullptr, fb, nullptr, nullptr, MR, FF, DM);
        mfma_gemm_kernel<2,1><<<(DM/128)*(MR/64), 256, 0, stream>>>(
            fb, pr_wt, pr_b + (size_t)l*DM, x, x, nullptr, nullptr, MR, DM, FF);
    }

    ln_kernel<<<MR/4, 256, 0, stream>>>(x, lnf_g, lnf_b, h);
    mfma_gemm_kernel<0,0><<<((VOC+127)/128)*(MR/128), 256, 0, stream>>>(
        h, lm_wt, nullptr, nullptr, logits, nullptr, part, MR, VOC, DM);

    zero_acc_kernel<<<1, 2, 0, stream>>>(lacc);
    loss_reduce_kernel<<<MR, 64, 0, stream>>>(part, logits, targets, lacc);
    loss_final_kernel<<<1, 1, 0, stream>>>(lacc, logits + (size_t)MR*VOC);
}